// Round 2
// baseline (235.563 us; speedup 1.0000x reference)
//
#include <hip/hip_runtime.h>
#include <math.h>

#define NB 32
#define CC 1024
#define SS 784
#define SP 832           // padded S (52*16); pad region of sa is zeroed
#define DD 128
#define KK 64
#define OUTD 1024
#define KD 8192          // K*D
#define NSPLIT 13        // vlad s-splits (64 s each)
#define PSPLIT 32        // split-K for projection (8192 = 32*256)

// workspace layout (BYTE offsets)  -- total ~29.5 MB (< 30.9 MB known-good)
#define OFF_XN    0                                   // bf16 (N,D,SP)
#define OFF_SA    (OFF_XN + NB*DD*SP*2)               // bf16 (N,K,SP)
#define OFF_WPK   (OFF_SA + NB*KK*SP*2)               // bf16 Wpool frag-packed (32*8*64*8)
#define OFF_WCK   (OFF_WPK + 32*8*64*8*2)             // bf16 Wconv frag-packed (16*64*8)
#define OFF_VLADP (OFF_WCK + 16*64*8*2)               // f32 (N,NSPLIT,KD) packed C-layout
#define OFF_SASUM (OFF_VLADP + NB*NSPLIT*KD*4)        // f32 (N,NSPLIT,K)
#define OFF_VLADN (OFF_SASUM + NB*NSPLIT*KK*4)        // f32 (N,KD)
#define OFF_OUTP  (OFF_VLADN + NB*KD*4)               // f32 (PSPLIT,N,OUT)

typedef __attribute__((ext_vector_type(8))) short bf16x8;   // 8 bf16 = 4 VGPRs
typedef __attribute__((ext_vector_type(4))) float f32x4;
typedef __attribute__((ext_vector_type(4))) unsigned int u32x4;

__device__ __forceinline__ unsigned int pk_bf16(float a, float b) {
    unsigned int ua = __builtin_bit_cast(unsigned int, a);
    unsigned int ub = __builtin_bit_cast(unsigned int, b);
    ua += 0x7FFFu + ((ua >> 16) & 1u);
    ub += 0x7FFFu + ((ub >> 16) & 1u);
    return (ua >> 16) | (ub & 0xFFFF0000u);
}
__device__ __forceinline__ unsigned short f2bf(float a) {
    unsigned int ua = __builtin_bit_cast(unsigned int, a);
    ua += 0x7FFFu + ((ua >> 16) & 1u);
    return (unsigned short)(ua >> 16);
}
__device__ __forceinline__ float bf2f(unsigned short u) {
    unsigned int v = ((unsigned int)u) << 16;
    return __builtin_bit_cast(float, v);
}

// ---------------------------------------------------------------------------
// c-permutation shared by pack_weights and pool staging:
// cb (0..127 = c-block of 8), elem j (0..7):
//   c = (cb>>5)*256 + ((cb>>3)&3)*64 + (cb&7) + 8*j
// (quarter q = cb>>5, wave W = (cb>>3)&3, r0 = cb&7).  GEMM contraction order
// over c is free as long as Wpk uses the SAME permutation.
// ---------------------------------------------------------------------------

// ---------------------------------------------------------------------------
// K1: pack Wpool (128x1024) and Wconv (64x128) into MFMA A-fragment-ordered
// bf16 arrays.  Wpk: [kt(32)][mt(8)][lane(64)][8] with permuted c; Wck
// unchanged: [tile(16)][lane(64)][8].
// ---------------------------------------------------------------------------
__global__ __launch_bounds__(256)
void pack_weights(const float* __restrict__ Wpool, const float* __restrict__ Wconv,
                  unsigned short* __restrict__ Wpk, unsigned short* __restrict__ Wck)
{
    const int b = blockIdx.x;
    const int t = threadIdx.x;
    if (b < 8) {
#pragma unroll
        for (int i = 0; i < 8; i++) {
            const int id = t + 256 * i;            // 0..2047
            const int ktl = id >> 9;               // 0..3
            const int mt  = (id >> 6) & 7;
            const int l   = id & 63;
            const int lm = l & 15, quad = l >> 4;
            const int kt = b * 4 + ktl;
            const int d = mt * 16 + lm;
            const int cb = kt * 4 + quad;          // 0..127
            const int base_c = (cb >> 5) * 256 + ((cb >> 3) & 3) * 64 + (cb & 7);
            float v[8];
#pragma unroll
            for (int j = 0; j < 8; j++) v[j] = Wpool[(size_t)d * CC + base_c + 8 * j];
            unsigned int* dst = (unsigned int*)&Wpk[(size_t)((kt * 8 + mt) * 64 + l) * 8];
            dst[0] = pk_bf16(v[0], v[1]); dst[1] = pk_bf16(v[2], v[3]);
            dst[2] = pk_bf16(v[4], v[5]); dst[3] = pk_bf16(v[6], v[7]);
        }
    } else {
#pragma unroll
        for (int i = 0; i < 4; i++) {
            const int id = t + 256 * i;            // 0..1023
            const int tile = id >> 6;
            const int l = id & 63;
            const int lm = l & 15, quad = l >> 4;
            const int k = (tile >> 2) * 16 + lm;
            const int d = (tile & 3) * 32 + quad * 8;
            const float4 v0 = *(const float4*)&Wconv[(size_t)k * DD + d];
            const float4 v1 = *(const float4*)&Wconv[(size_t)k * DD + d + 4];
            unsigned int* dst = (unsigned int*)&Wck[(size_t)(tile * 64 + l) * 8];
            dst[0] = pk_bf16(v0.x, v0.y); dst[1] = pk_bf16(v0.z, v0.w);
            dst[2] = pk_bf16(v1.x, v1.y); dst[3] = pk_bf16(v1.z, v1.w);
        }
    }
}

// ---------------------------------------------------------------------------
// K2 v3: pool GEMM + bias + L2-norm + assign GEMM + softmax.
// Block tile 128d x 32s, grid (26, N) = 832 blocks (tile 24 mixed/clamped,
// tile 25 pure pad).  Staging: every wave-instruction reads 8 consecutive
// c-rows x full 128B line (lane = (row 8)x(16B chunk 8)); c-permutation pi
// keeps fragment packs 8-wide per thread.  LDS sigma-swizzle s^((s>>3)&3)
// is conflict-free on BOTH the pack writes and the b128 fragment reads.
// 4 c-quarters, double-buffered LDS (2x16KB); Wpk prefetch depth 2.
// ---------------------------------------------------------------------------
__global__ __launch_bounds__(256, 3)
void pool_norm_assign(const float* __restrict__ x, const unsigned short* __restrict__ Wpk,
                      const float* __restrict__ bpool, const unsigned short* __restrict__ Wck,
                      const float* __restrict__ bconv,
                      unsigned short* __restrict__ xn, unsigned short* __restrict__ sa)
{
    const int n  = blockIdx.y;
    const int s0 = blockIdx.x * 32;
    const int t  = threadIdx.x;
    const int l  = t & 63;
    const int w  = t >> 6;       // wave 0..3
    const int lm = l & 15;
    const int quad = l >> 4;

    __shared__ alignas(16) unsigned short Bst[2][32 * 32 * 8];  // 2 x 16 KB
    __shared__ alignas(16) unsigned short xnT[16 * 32 * 8];     // 8 KB [dblk][s][8]
    __shared__ float red[4][32];
    __shared__ float sums[4][32];

    unsigned short* xnp = xn + (size_t)n * DD * SP;
    unsigned short* sap = sa + (size_t)n * KK * SP;

    if (s0 >= SS) {
        // pure-pad tile (s0 = 800): zero xn and sa for s 800..831, exit.
        const u32x4 z = (u32x4){0u, 0u, 0u, 0u};
#pragma unroll
        for (int pp = 0; pp < 2; pp++) {
            const int idx = t + 256 * pp;
            *(u32x4*)&xnp[(size_t)(idx >> 2) * SP + s0 + (idx & 3) * 8] = z;
        }
        *(u32x4*)&sap[(size_t)(t >> 2) * SP + s0 + (t & 3) * 8] = z;
        return;
    }

    const int r0 = (l >> 3) & 7;   // row-in-group 0..7
    const int se = l & 7;          // 16B s-chunk 0..7
    // chunk-aligned clamp for the mixed tile 24 (s 784..799 OOB -> reload
    // an in-bounds chunk; values garbage-but-finite, neutralized by sa=0)
    int sc = s0 + se * 4;
    if (sc + 4 > SS) sc = s0 + (se & 3) * 4;
    const float* xw = x + (size_t)n * CC * SS + sc;
    const int crow0 = w * 64 + r0;                 // + q*256 + j*8 = global c row

    // ---- stage quarter 0
    f32x4 g[8];
#pragma unroll
    for (int j = 0; j < 8; j++)
        g[j] = *(const f32x4*)&xw[(size_t)(crow0 + j * 8) * SS];
    {
#pragma unroll
        for (int ss = 0; ss < 4; ss++) {
            const int s = se * 4 + ss;
            const int sig = s ^ ((s >> 3) & 3);
            unsigned int* dst = (unsigned int*)&Bst[0][(size_t)((w * 8 + r0) * 32 + sig) * 8];
            dst[0] = pk_bf16(g[0][ss], g[1][ss]); dst[1] = pk_bf16(g[2][ss], g[3][ss]);
            dst[2] = pk_bf16(g[4][ss], g[5][ss]); dst[3] = pk_bf16(g[6][ss], g[7][ss]);
        }
    }
    __syncthreads();

    f32x4 acc[2][2];   // [i=d-tile][h=s-sub]
#pragma unroll
    for (int i = 0; i < 2; i++)
#pragma unroll
        for (int h = 0; h < 2; h++) acc[i][h] = (f32x4){0.f, 0.f, 0.f, 0.f};

    bf16x8 abuf[2][2];  // prefetch depth 2: [kt&1][i]
#pragma unroll
    for (int p = 0; p < 2; p++)
#pragma unroll
        for (int i = 0; i < 2; i++)
            abuf[p][i] = *(const bf16x8*)&Wpk[(size_t)((p * 8 + w * 2 + i) * 64 + l) * 8];

    for (int q = 0; q < 4; ++q) {
        // issue next-quarter x loads (consumed only after this K-loop)
        if (q < 3) {
#pragma unroll
            for (int j = 0; j < 8; j++)
                g[j] = *(const f32x4*)&xw[(size_t)((q + 1) * 256 + crow0 + j * 8) * SS];
        }
#pragma unroll
        for (int ktq = 0; ktq < 8; ++ktq) {
            const int kt = q * 8 + ktq;
            const bf16x8 a0 = abuf[kt & 1][0], a1 = abuf[kt & 1][1];
            if (kt < 30) {
#pragma unroll
                for (int i = 0; i < 2; i++)
                    abuf[kt & 1][i] = *(const bf16x8*)&Wpk[(size_t)(((kt + 2) * 8 + w * 2 + i) * 64 + l) * 8];
            }
#pragma unroll
            for (int h = 0; h < 2; h++) {
                const int s = h * 16 + lm;
                const int sig = s ^ ((s >> 3) & 3);
                const bf16x8 bf = *(const bf16x8*)&Bst[q & 1][(size_t)((ktq * 4 + quad) * 32 + sig) * 8];
                acc[0][h] = __builtin_amdgcn_mfma_f32_16x16x32_bf16(a0, bf, acc[0][h], 0, 0, 0);
                acc[1][h] = __builtin_amdgcn_mfma_f32_16x16x32_bf16(a1, bf, acc[1][h], 0, 0, 0);
            }
        }
        if (q < 3) {
#pragma unroll
            for (int ss = 0; ss < 4; ss++) {
                const int s = se * 4 + ss;
                const int sig = s ^ ((s >> 3) & 3);
                unsigned int* dst = (unsigned int*)&Bst[(q + 1) & 1][(size_t)((w * 8 + r0) * 32 + sig) * 8];
                dst[0] = pk_bf16(g[0][ss], g[1][ss]); dst[1] = pk_bf16(g[2][ss], g[3][ss]);
                dst[2] = pk_bf16(g[4][ss], g[5][ss]); dst[3] = pk_bf16(g[6][ss], g[7][ss]);
            }
        }
        __syncthreads();
    }

    // ---- PHASE 3a: bias + L2-norm over d.  C: d=(2w+i)*16+quad*4+r, s=h*16+lm
    float vals[2][2][4];
    float ssq[2] = {0.f, 0.f};
#pragma unroll
    for (int i = 0; i < 2; i++)
#pragma unroll
        for (int h = 0; h < 2; h++)
#pragma unroll
            for (int r = 0; r < 4; r++) {
                const int d = (w * 2 + i) * 16 + quad * 4 + r;
                const float v = acc[i][h][r] + bpool[d];
                vals[i][h][r] = v; ssq[h] += v * v;
            }
#pragma unroll
    for (int h = 0; h < 2; h++) {
        ssq[h] += __shfl_xor(ssq[h], 16, 64);
        ssq[h] += __shfl_xor(ssq[h], 32, 64);
    }
    if (quad == 0) { red[w][lm] = ssq[0]; red[w][16 + lm] = ssq[1]; }
    __syncthreads();
    float scale[2];
#pragma unroll
    for (int h = 0; h < 2; h++) {
        const int sl = h * 16 + lm;
        scale[h] = 1.f / fmaxf(sqrtf(red[0][sl] + red[1][sl] + red[2][sl] + red[3][sl]), 1e-12f);
    }
#pragma unroll
    for (int i = 0; i < 2; i++)
#pragma unroll
        for (int h = 0; h < 2; h++)
#pragma unroll
            for (int r = 0; r < 4; r++) {
                const int d = (w * 2 + i) * 16 + quad * 4 + r;
                const int sg = s0 + h * 16 + lm;
                const float v = vals[i][h][r] * scale[h];
                xnp[(size_t)d * SP + sg] = f2bf(v);
                xnT[(size_t)(((d >> 3) * 32) + h * 16 + lm) * 8 + (d & 7)] = f2bf(v);
            }
    __syncthreads();

    // ---- PHASE 3b: assign GEMM (64k x 32s), wave w -> k-tile w
    f32x4 acc2[2];
    acc2[0] = (f32x4){0.f, 0.f, 0.f, 0.f};
    acc2[1] = (f32x4){0.f, 0.f, 0.f, 0.f};
#pragma unroll
    for (int dsv = 0; dsv < 4; dsv++) {
        const bf16x8 afrag = *(const bf16x8*)&Wck[(size_t)((w * 4 + dsv) * 64 + l) * 8];
#pragma unroll
        for (int h = 0; h < 2; h++) {
            const bf16x8 bfrag = *(const bf16x8*)&xnT[(size_t)((dsv * 4 + quad) * 32 + h * 16 + lm) * 8];
            acc2[h] = __builtin_amdgcn_mfma_f32_16x16x32_bf16(afrag, bfrag, acc2[h], 0, 0, 0);
        }
    }
    // softmax over k (|logits| small since x-hat unit-norm: no max-sub needed)
    float e[2][4]; float ps[2] = {0.f, 0.f};
#pragma unroll
    for (int h = 0; h < 2; h++)
#pragma unroll
        for (int r = 0; r < 4; r++) {
            const int k = w * 16 + quad * 4 + r;
            e[h][r] = expf(acc2[h][r] + bconv[k]);
            ps[h] += e[h][r];
        }
#pragma unroll
    for (int h = 0; h < 2; h++) {
        ps[h] += __shfl_xor(ps[h], 16, 64);
        ps[h] += __shfl_xor(ps[h], 32, 64);
    }
    if (quad == 0) { sums[w][lm] = ps[0]; sums[w][16 + lm] = ps[1]; }
    __syncthreads();
#pragma unroll
    for (int h = 0; h < 2; h++) {
        const int sl = h * 16 + lm;
        const int sg = s0 + sl;
        const float inv = 1.f / (sums[0][sl] + sums[1][sl] + sums[2][sl] + sums[3][sl]);
        const bool val2 = sg < SS;
#pragma unroll
        for (int r = 0; r < 4; r++) {
            const int k = w * 16 + quad * 4 + r;
            sap[(size_t)k * SP + sg] = val2 ? f2bf(e[h][r] * inv) : (unsigned short)0;
        }
    }
}

// ---------------------------------------------------------------------------
// K3: vlad GEMM (MFMA, fragment loads direct from global, no LDS, no barrier):
// C stored PACKED: vp[(kq*DD+d)*4 + r], k = kq*4+r -> 16B f32x4 stores.
// grid (NSPLIT, N) = 416 blocks; wave tile 32k x 64d.
// ---------------------------------------------------------------------------
__global__ __launch_bounds__(256)
void vlad_mfma(const unsigned short* __restrict__ xn, const unsigned short* __restrict__ sa,
               float* __restrict__ vladp, float* __restrict__ sasump)
{
    const int p = blockIdx.x;
    const int n = blockIdx.y;
    const int t = threadIdx.x;
    const int l = t & 63;
    const int w = t >> 6;
    const int kth = w & 1, nh = w >> 1;
    const int lm = l & 15, quad = l >> 4;

    const unsigned short* sap = sa + (size_t)n * KK * SP;
    const unsigned short* xnp = xn + (size_t)n * DD * SP;

    f32x4 acc[2][4];
#pragma unroll
    for (int j = 0; j < 2; j++)
#pragma unroll
        for (int i = 0; i < 4; i++) acc[j][i] = (f32x4){0.f, 0.f, 0.f, 0.f};

#pragma unroll
    for (int st = 0; st < 2; st++) {
        const int sb = p * 64 + st * 32 + quad * 8;
        bf16x8 af[2], bfv[4];
#pragma unroll
        for (int j = 0; j < 2; j++)
            af[j] = *(const bf16x8*)&sap[(size_t)((kth * 2 + j) * 16 + lm) * SP + sb];
#pragma unroll
        for (int i = 0; i < 4; i++)
            bfv[i] = *(const bf16x8*)&xnp[(size_t)((nh * 4 + i) * 16 + lm) * SP + sb];
#pragma unroll
        for (int j = 0; j < 2; j++)
#pragma unroll
            for (int i = 0; i < 4; i++)
                acc[j][i] = __builtin_amdgcn_mfma_f32_16x16x32_bf16(af[j], bfv[i], acc[j][i], 0, 0, 0);
    }

    float* vp = vladp + ((size_t)n * NSPLIT + p) * KD;
#pragma unroll
    for (int j = 0; j < 2; j++)
#pragma unroll
        for (int i = 0; i < 4; i++) {
            const int kq = (kth * 2 + j) * 4 + quad;          // k = kq*4 + r
            const int d  = (nh * 4 + i) * 16 + lm;
            *(f32x4*)&vp[(size_t)(kq * DD + d) * 4] = acc[j][i];
        }

    if (t < KK) {
        float sm = 0.f;
        const unsigned short* rp = &sap[(size_t)t * SP + p * 64];
#pragma unroll
        for (int c8 = 0; c8 < 8; c8++) {
            const bf16x8 v = *(const bf16x8*)&rp[c8 * 8];
#pragma unroll
            for (int j = 0; j < 8; j++) sm += bf2f((unsigned short)v[j]);
        }
        sasump[((size_t)n * NSPLIT + p) * KK + t] = sm;
    }
}

// ---------------------------------------------------------------------------
// K4: reduce NSPLIT partials (f32x4 vector reads), subtract centroids*sasum,
// L2-norm over k, write vladn.  grid (DD/16=8, N) = 256 blocks.
// thread: kq = t&15 (k=kq*4+r), d = dg*16 + (t>>4).
// ---------------------------------------------------------------------------
__global__ __launch_bounds__(256)
void vlad_finish(const float* __restrict__ vladp, const float* __restrict__ sasump,
                 const float* __restrict__ centroids, float* __restrict__ vladn)
{
    const int dg = blockIdx.x;
    const int n  = blockIdx.y;
    const int t  = threadIdx.x;
    const int kq = t & 15;
    const int d  = dg * 16 + (t >> 4);

    __shared__ float sas[KK];
    if (t < KK) {
        float sm = 0.f;
#pragma unroll
        for (int p = 0; p < NSPLIT; p++) sm += sasump[((size_t)n * NSPLIT + p) * KK + t];
        sas[t] = sm;
    }
    __syncthreads();

    f32x4 v = (f32x4){0.f, 0.f, 0.f, 0.f};
#pragma unroll
    for (int p = 0; p < NSPLIT; p++) {
        const f32x4 pr = *(const f32x4*)&vladp[((size_t)n * NSPLIT + p) * KD + (size_t)(kq * DD + d) * 4];
        v += pr;
    }
#pragma unroll
    for (int r = 0; r < 4; r++)
        v[r] -= centroids[(size_t)(kq * 4 + r) * DD + d] * sas[kq * 4 + r];

    float ssq = v[0] * v[0] + v[1] * v[1] + v[2] * v[2] + v[3] * v[3];
    ssq += __shfl_xor(ssq, 1, 64);
    ssq += __shfl_xor(ssq, 2, 64);
    ssq += __shfl_xor(ssq, 4, 64);
    ssq += __shfl_xor(ssq, 8, 64);               // full 16-kq group for this d
    const float scale = 1.f / fmaxf(sqrtf(ssq), 1e-12f);

    float* vo = vladn + (size_t)n * KD;
#pragma unroll
    for (int r = 0; r < 4; r++)
        vo[(size_t)(kq * 4 + r) * DD + d] = v[r] * scale;
}

// ---------------------------------------------------------------------------
// K5: projection via MFMA, barrier-free, no LDS.
// out[n][o] = vladn[n][c] . Wproj[o][c]; A=vladn (m=n), B=Wproj (ndim=o), k=c.
// grid (OUT/64=16, PSPLIT=32) = 512 blocks; 8 K-steps of 32 c; operands packed
// to bf16 in-register from independent float4 loads.
// ---------------------------------------------------------------------------
__global__ __launch_bounds__(256)
void proj_mfma(const float* __restrict__ vladn, const float* __restrict__ Wproj,
               float* __restrict__ outp)
{
    const int o0 = blockIdx.x * 64;
    const int c0 = blockIdx.y * (KD / PSPLIT);   // 256-wide c slice
    const int t  = threadIdx.x;
    const int l  = t & 63;
    const int w  = t >> 6;
    const int lm = l & 15, quad = l >> 4;
    const int o  = o0 + w * 16 + lm;

    f32x4 acc[2];
    acc[0] = (f32x4){0.f, 0.f, 0.f, 0.f};
    acc[1] = (f32x4){0.f, 0.f, 0.f, 0.f};

#pragma unroll 2
    for (int kt = 0; kt < 8; kt++) {
        const int c = c0 + kt * 32 + quad * 8;
        const float4 b0 = *(const float4*)&Wproj[(size_t)o * KD + c];
        const float4 b1 = *(const float4*)&Wproj[(size_t)o * KD + c + 4];
        float4 a00 = *(const float4*)&vladn[(size_t)(0 * 16 + lm) * KD + c];
        float4 a01 = *(const float4*)&vladn[(size_t)(0 * 16 + lm) * KD + c + 4];
        float4 a10 = *(const float4*)&vladn[(size_t)(16 + lm) * KD + c];
        float4 a11 = *(const float4*)&vladn[(size_t)(16 + lm) * KD + c + 4];
        union { unsigned int u[4]; bf16x8 v; } ub, ua0, ua1;
        ub.u[0] = pk_bf16(b0.x, b0.y); ub.u[1] = pk_bf16(b0.z, b0.w);
        ub.u[2] = pk_bf16(b1.x, b1.y); ub.u[3] = pk_bf16(b1.z, b1.w);
        ua0.u[0] = pk_bf16(a00.x, a00.y); ua0.u[1] = pk_bf16(a00.z, a00.w);
        ua0.u[2] = pk_bf16(a01.x, a01.y); ua0.u[3] = pk_bf16(a01.z, a01.w);
        ua1.u[0] = pk_bf16(a10.x, a10.y); ua1.u[1] = pk_bf16(a10.z, a10.w);
        ua1.u[2] = pk_bf16(a11.x, a11.y); ua1.u[3] = pk_bf16(a11.z, a11.w);
        acc[0] = __builtin_amdgcn_mfma_f32_16x16x32_bf16(ua0.v, ub.v, acc[0], 0, 0, 0);
        acc[1] = __builtin_amdgcn_mfma_f32_16x16x32_bf16(ua1.v, ub.v, acc[1], 0, 0, 0);
    }

    // C layout: col lm -> o (matches B), row quad*4+r -> n = a*16+quad*4+r
#pragma unroll
    for (int a = 0; a < 2; a++)
#pragma unroll
        for (int r = 0; r < 4; r++) {
            const int nn = a * 16 + quad * 4 + r;
            outp[((size_t)blockIdx.y * NB + nn) * OUTD + o] = acc[a][r];
        }
}

// ---------------------------------------------------------------------------
// K6: sum projection partials + bproj, final L2 norm over OUT, write d_out.
// ---------------------------------------------------------------------------
__global__ __launch_bounds__(256)
void final_norm_kernel(const float* __restrict__ outp, const float* __restrict__ bproj,
                       float* __restrict__ out)
{
    const int n = blockIdx.x;
    const int t = threadIdx.x;
    const int o4 = t * 4;

    float4 a = *(const float4*)&bproj[o4];
#pragma unroll
    for (int p = 0; p < PSPLIT; p++) {
        const float4 pr = *(const float4*)&outp[((size_t)p * NB + n) * OUTD + o4];
        a.x += pr.x; a.y += pr.y; a.z += pr.z; a.w += pr.w;
    }
    float ssp = a.x * a.x + a.y * a.y + a.z * a.z + a.w * a.w;
#pragma unroll
    for (int off = 32; off > 0; off >>= 1) ssp += __shfl_down(ssp, off, 64);
    __shared__ float rs[4];
    if ((t & 63) == 0) rs[t >> 6] = ssp;
    __syncthreads();
    const float total = rs[0] + rs[1] + rs[2] + rs[3];
    const float scale = 1.f / fmaxf(sqrtf(total), 1e-12f);
    float4 o;
    o.x = a.x * scale; o.y = a.y * scale; o.z = a.z * scale; o.w = a.w * scale;
    *(float4*)&out[(size_t)n * OUTD + o4] = o;
}

// ---------------------------------------------------------------------------
extern "C" void kernel_launch(void* const* d_in, const int* in_sizes, int n_in,
                              void* d_out, int out_size, void* d_ws, size_t ws_size,
                              hipStream_t stream)
{
    const float* x         = (const float*)d_in[0];
    const float* Wpool     = (const float*)d_in[1];
    const float* bpool     = (const float*)d_in[2];
    const float* Wconv     = (const float*)d_in[3];
    const float* bconv     = (const float*)d_in[4];
    const float* centroids = (const float*)d_in[5];
    const float* Wproj     = (const float*)d_in[6];
    const float* bproj     = (const float*)d_in[7];
    float* out = (float*)d_out;
    char*  wsb = (char*)d_ws;

    unsigned short* xn     = (unsigned short*)(wsb + OFF_XN);
    unsigned short* sa     = (unsigned short*)(wsb + OFF_SA);
    unsigned short* Wpk    = (unsigned short*)(wsb + OFF_WPK);
    unsigned short* Wck    = (unsigned short*)(wsb + OFF_WCK);
    float*          vladp  = (float*)(wsb + OFF_VLADP);
    float*          sasump = (float*)(wsb + OFF_SASUM);
    float*          vladn  = (float*)(wsb + OFF_VLADN);
    float*          outp   = (float*)(wsb + OFF_OUTP);

    pack_weights<<<dim3(9), 256, 0, stream>>>(Wpool, Wconv, Wpk, Wck);
    pool_norm_assign<<<dim3(26, NB), 256, 0, stream>>>(x, Wpk, bpool, Wck, bconv, xn, sa);
    vlad_mfma<<<dim3(NSPLIT, NB), 256, 0, stream>>>(xn, sa, vladp, sasump);
    vlad_finish<<<dim3(DD / 16, NB), 256, 0, stream>>>(vladp, sasump, centroids, vladn);
    proj_mfma<<<dim3(OUTD / 64, PSPLIT), 256, 0, stream>>>(vladn, Wproj, outp);
    final_norm_kernel<<<dim3(NB), 256, 0, stream>>>(outp, bproj, out);
}

// Round 3
// 228.861 us; speedup vs baseline: 1.0293x; 1.0293x over previous
//
#include <hip/hip_runtime.h>
#include <math.h>

#define NB 32
#define CC 1024
#define SS 784
#define SP 832           // padded S (52*16); pad region of sa is zeroed
#define DD 128
#define KK 64
#define OUTD 1024
#define KD 8192          // K*D
#define NSPLIT 13        // vlad s-splits (64 s each)
#define PSPLIT 32        // split-K for projection (8192 = 32*256)

// workspace layout (BYTE offsets)  -- total ~29.5 MB (< 30.9 MB known-good)
#define OFF_XN    0                                   // bf16 (N,D,SP)
#define OFF_SA    (OFF_XN + NB*DD*SP*2)               // bf16 (N,K,SP)
#define OFF_WPK   (OFF_SA + NB*KK*SP*2)               // bf16 Wpool frag-packed (32*8*64*8)
#define OFF_WCK   (OFF_WPK + 32*8*64*8*2)             // bf16 Wconv frag-packed (16*64*8)
#define OFF_VLADP (OFF_WCK + 16*64*8*2)               // f32 (N,NSPLIT,KD) packed C-layout
#define OFF_SASUM (OFF_VLADP + NB*NSPLIT*KD*4)        // f32 (N,NSPLIT,K)
#define OFF_VLADN (OFF_SASUM + NB*NSPLIT*KK*4)        // f32 (N,KD)
#define OFF_OUTP  (OFF_VLADN + NB*KD*4)               // f32 (PSPLIT,N,OUT)

typedef __attribute__((ext_vector_type(8))) short bf16x8;   // 8 bf16 = 4 VGPRs
typedef __attribute__((ext_vector_type(4))) float f32x4;
typedef __attribute__((ext_vector_type(4))) unsigned int u32x4;

__device__ __forceinline__ unsigned int pk_bf16(float a, float b) {
    unsigned int ua = __builtin_bit_cast(unsigned int, a);
    unsigned int ub = __builtin_bit_cast(unsigned int, b);
    ua += 0x7FFFu + ((ua >> 16) & 1u);
    ub += 0x7FFFu + ((ub >> 16) & 1u);
    return (ua >> 16) | (ub & 0xFFFF0000u);
}
__device__ __forceinline__ unsigned short f2bf(float a) {
    unsigned int ua = __builtin_bit_cast(unsigned int, a);
    ua += 0x7FFFu + ((ua >> 16) & 1u);
    return (unsigned short)(ua >> 16);
}
__device__ __forceinline__ float bf2f(unsigned short u) {
    unsigned int v = ((unsigned int)u) << 16;
    return __builtin_bit_cast(float, v);
}

// ---------------------------------------------------------------------------
// c-permutation shared by pack_weights and pool staging:
// cb (0..127 = c-block of 8), elem j (0..7):
//   c = (cb>>5)*256 + ((cb>>3)&3)*64 + (cb&7) + 8*j
// GEMM contraction order over c is free as long as Wpk uses the SAME perm.
// ---------------------------------------------------------------------------

// ---------------------------------------------------------------------------
// K1: pack Wpool (128x1024) and Wconv (64x128) into MFMA A-fragment-ordered
// bf16 arrays.  Wpk: [kt(32)][mt(8)][lane(64)][8] with permuted c; Wck:
// [tile(16)][lane(64)][8].
// ---------------------------------------------------------------------------
__global__ __launch_bounds__(256)
void pack_weights(const float* __restrict__ Wpool, const float* __restrict__ Wconv,
                  unsigned short* __restrict__ Wpk, unsigned short* __restrict__ Wck)
{
    const int b = blockIdx.x;
    const int t = threadIdx.x;
    if (b < 8) {
#pragma unroll
        for (int i = 0; i < 8; i++) {
            const int id = t + 256 * i;            // 0..2047
            const int ktl = id >> 9;               // 0..3
            const int mt  = (id >> 6) & 7;
            const int l   = id & 63;
            const int lm = l & 15, quad = l >> 4;
            const int kt = b * 4 + ktl;
            const int d = mt * 16 + lm;
            const int cb = kt * 4 + quad;          // 0..127
            const int base_c = (cb >> 5) * 256 + ((cb >> 3) & 3) * 64 + (cb & 7);
            float v[8];
#pragma unroll
            for (int j = 0; j < 8; j++) v[j] = Wpool[(size_t)d * CC + base_c + 8 * j];
            unsigned int* dst = (unsigned int*)&Wpk[(size_t)((kt * 8 + mt) * 64 + l) * 8];
            dst[0] = pk_bf16(v[0], v[1]); dst[1] = pk_bf16(v[2], v[3]);
            dst[2] = pk_bf16(v[4], v[5]); dst[3] = pk_bf16(v[6], v[7]);
        }
    } else {
#pragma unroll
        for (int i = 0; i < 4; i++) {
            const int id = t + 256 * i;            // 0..1023
            const int tile = id >> 6;
            const int l = id & 63;
            const int lm = l & 15, quad = l >> 4;
            const int k = (tile >> 2) * 16 + lm;
            const int d = (tile & 3) * 32 + quad * 8;
            const float4 v0 = *(const float4*)&Wconv[(size_t)k * DD + d];
            const float4 v1 = *(const float4*)&Wconv[(size_t)k * DD + d + 4];
            unsigned int* dst = (unsigned int*)&Wck[(size_t)(tile * 64 + l) * 8];
            dst[0] = pk_bf16(v0.x, v0.y); dst[1] = pk_bf16(v0.z, v0.w);
            dst[2] = pk_bf16(v1.x, v1.y); dst[3] = pk_bf16(v1.z, v1.w);
        }
    }
}

// ---------------------------------------------------------------------------
// K2 v4: same math/layout as v3 (bit-identical output), but with
// sched_barrier(0) fences pinning issue-early/consume-late so the compiler
// cannot sink the staging loads to their use site (R1/R2 showed VGPR=40/68
// -> loads serialized at full HBM latency).  Wpk prefetch depth 2 -> 4.
// ---------------------------------------------------------------------------
__global__ __launch_bounds__(256, 3)
void pool_norm_assign(const float* __restrict__ x, const unsigned short* __restrict__ Wpk,
                      const float* __restrict__ bpool, const unsigned short* __restrict__ Wck,
                      const float* __restrict__ bconv,
                      unsigned short* __restrict__ xn, unsigned short* __restrict__ sa)
{
    const int n  = blockIdx.y;
    const int s0 = blockIdx.x * 32;
    const int t  = threadIdx.x;
    const int l  = t & 63;
    const int w  = t >> 6;       // wave 0..3
    const int lm = l & 15;
    const int quad = l >> 4;

    __shared__ alignas(16) unsigned short Bst[2][32 * 32 * 8];  // 2 x 16 KB
    __shared__ alignas(16) unsigned short xnT[16 * 32 * 8];     // 8 KB [dblk][s][8]
    __shared__ float red[4][32];
    __shared__ float sums[4][32];

    unsigned short* xnp = xn + (size_t)n * DD * SP;
    unsigned short* sap = sa + (size_t)n * KK * SP;

    if (s0 >= SS) {
        // pure-pad tile (s0 = 800): zero xn and sa for s 800..831, exit.
        const u32x4 z = (u32x4){0u, 0u, 0u, 0u};
#pragma unroll
        for (int pp = 0; pp < 2; pp++) {
            const int idx = t + 256 * pp;
            *(u32x4*)&xnp[(size_t)(idx >> 2) * SP + s0 + (idx & 3) * 8] = z;
        }
        *(u32x4*)&sap[(size_t)(t >> 2) * SP + s0 + (t & 3) * 8] = z;
        return;
    }

    const int r0 = (l >> 3) & 7;   // row-in-group 0..7
    const int se = l & 7;          // 16B s-chunk 0..7
    // chunk-aligned clamp for the mixed tile 24 (s 784..799 OOB -> reload
    // an in-bounds chunk; values garbage-but-finite, neutralized by sa=0)
    int sc = s0 + se * 4;
    if (sc + 4 > SS) sc = s0 + (se & 3) * 4;
    const float* xw = x + (size_t)n * CC * SS + sc;
    const int crow0 = w * 64 + r0;                 // + q*256 + j*8 = global c row

    // ---- prologue: issue quarter-0 x loads + Wpk depth-4 prefetch, THEN pack
    f32x4 g[8];
#pragma unroll
    for (int j = 0; j < 8; j++)
        g[j] = *(const f32x4*)&xw[(size_t)(crow0 + j * 8) * SS];

    bf16x8 abuf[4][2];  // prefetch depth 4: slot kt&3
#pragma unroll
    for (int p = 0; p < 4; p++)
#pragma unroll
        for (int i = 0; i < 2; i++)
            abuf[p][i] = *(const bf16x8*)&Wpk[(size_t)((p * 8 + w * 2 + i) * 64 + l) * 8];

    __builtin_amdgcn_sched_barrier(0);

#pragma unroll
    for (int ss = 0; ss < 4; ss++) {
        const int s = se * 4 + ss;
        const int sig = s ^ ((s >> 3) & 3);
        unsigned int* dst = (unsigned int*)&Bst[0][(size_t)((w * 8 + r0) * 32 + sig) * 8];
        dst[0] = pk_bf16(g[0][ss], g[1][ss]); dst[1] = pk_bf16(g[2][ss], g[3][ss]);
        dst[2] = pk_bf16(g[4][ss], g[5][ss]); dst[3] = pk_bf16(g[6][ss], g[7][ss]);
    }
    __syncthreads();

    f32x4 acc[2][2];   // [i=d-tile][h=s-sub]
#pragma unroll
    for (int i = 0; i < 2; i++)
#pragma unroll
        for (int h = 0; h < 2; h++) acc[i][h] = (f32x4){0.f, 0.f, 0.f, 0.f};

    for (int q = 0; q < 4; ++q) {
        // issue next-quarter x loads (consumed only after this K-loop)
        if (q < 3) {
#pragma unroll
            for (int j = 0; j < 8; j++)
                g[j] = *(const f32x4*)&xw[(size_t)((q + 1) * 256 + crow0 + j * 8) * SS];
        }
        __builtin_amdgcn_sched_barrier(0);   // loads stay ABOVE the K-loop
#pragma unroll
        for (int ktq = 0; ktq < 8; ++ktq) {
            const int kt = q * 8 + ktq;
            const bf16x8 a0 = abuf[ktq & 3][0], a1 = abuf[ktq & 3][1];
            if (kt < 28) {
#pragma unroll
                for (int i = 0; i < 2; i++)
                    abuf[ktq & 3][i] = *(const bf16x8*)&Wpk[(size_t)(((kt + 4) * 8 + w * 2 + i) * 64 + l) * 8];
            }
#pragma unroll
            for (int h = 0; h < 2; h++) {
                const int s = h * 16 + lm;
                const int sig = s ^ ((s >> 3) & 3);
                const bf16x8 bf = *(const bf16x8*)&Bst[q & 1][(size_t)((ktq * 4 + quad) * 32 + sig) * 8];
                acc[0][h] = __builtin_amdgcn_mfma_f32_16x16x32_bf16(a0, bf, acc[0][h], 0, 0, 0);
                acc[1][h] = __builtin_amdgcn_mfma_f32_16x16x32_bf16(a1, bf, acc[1][h], 0, 0, 0);
            }
        }
        __builtin_amdgcn_sched_barrier(0);   // packs stay BELOW the K-loop
        if (q < 3) {
#pragma unroll
            for (int ss = 0; ss < 4; ss++) {
                const int s = se * 4 + ss;
                const int sig = s ^ ((s >> 3) & 3);
                unsigned int* dst = (unsigned int*)&Bst[(q + 1) & 1][(size_t)((w * 8 + r0) * 32 + sig) * 8];
                dst[0] = pk_bf16(g[0][ss], g[1][ss]); dst[1] = pk_bf16(g[2][ss], g[3][ss]);
                dst[2] = pk_bf16(g[4][ss], g[5][ss]); dst[3] = pk_bf16(g[6][ss], g[7][ss]);
            }
        }
        __syncthreads();
    }

    // ---- PHASE 3a: bias + L2-norm over d.  C: d=(2w+i)*16+quad*4+r, s=h*16+lm
    float vals[2][2][4];
    float ssq[2] = {0.f, 0.f};
#pragma unroll
    for (int i = 0; i < 2; i++)
#pragma unroll
        for (int h = 0; h < 2; h++)
#pragma unroll
            for (int r = 0; r < 4; r++) {
                const int d = (w * 2 + i) * 16 + quad * 4 + r;
                const float v = acc[i][h][r] + bpool[d];
                vals[i][h][r] = v; ssq[h] += v * v;
            }
#pragma unroll
    for (int h = 0; h < 2; h++) {
        ssq[h] += __shfl_xor(ssq[h], 16, 64);
        ssq[h] += __shfl_xor(ssq[h], 32, 64);
    }
    if (quad == 0) { red[w][lm] = ssq[0]; red[w][16 + lm] = ssq[1]; }
    __syncthreads();
    float scale[2];
#pragma unroll
    for (int h = 0; h < 2; h++) {
        const int sl = h * 16 + lm;
        scale[h] = 1.f / fmaxf(sqrtf(red[0][sl] + red[1][sl] + red[2][sl] + red[3][sl]), 1e-12f);
    }
#pragma unroll
    for (int i = 0; i < 2; i++)
#pragma unroll
        for (int h = 0; h < 2; h++)
#pragma unroll
            for (int r = 0; r < 4; r++) {
                const int d = (w * 2 + i) * 16 + quad * 4 + r;
                const int sg = s0 + h * 16 + lm;
                const float v = vals[i][h][r] * scale[h];
                xnp[(size_t)d * SP + sg] = f2bf(v);
                xnT[(size_t)(((d >> 3) * 32) + h * 16 + lm) * 8 + (d & 7)] = f2bf(v);
            }
    __syncthreads();

    // ---- PHASE 3b: assign GEMM (64k x 32s), wave w -> k-tile w
    f32x4 acc2[2];
    acc2[0] = (f32x4){0.f, 0.f, 0.f, 0.f};
    acc2[1] = (f32x4){0.f, 0.f, 0.f, 0.f};
#pragma unroll
    for (int dsv = 0; dsv < 4; dsv++) {
        const bf16x8 afrag = *(const bf16x8*)&Wck[(size_t)((w * 4 + dsv) * 64 + l) * 8];
#pragma unroll
        for (int h = 0; h < 2; h++) {
            const bf16x8 bfrag = *(const bf16x8*)&xnT[(size_t)((dsv * 4 + quad) * 32 + h * 16 + lm) * 8];
            acc2[h] = __builtin_amdgcn_mfma_f32_16x16x32_bf16(afrag, bfrag, acc2[h], 0, 0, 0);
        }
    }
    // softmax over k (|logits| small since x-hat unit-norm: no max-sub needed)
    float e[2][4]; float ps[2] = {0.f, 0.f};
#pragma unroll
    for (int h = 0; h < 2; h++)
#pragma unroll
        for (int r = 0; r < 4; r++) {
            const int k = w * 16 + quad * 4 + r;
            e[h][r] = expf(acc2[h][r] + bconv[k]);
            ps[h] += e[h][r];
        }
#pragma unroll
    for (int h = 0; h < 2; h++) {
        ps[h] += __shfl_xor(ps[h], 16, 64);
        ps[h] += __shfl_xor(ps[h], 32, 64);
    }
    if (quad == 0) { sums[w][lm] = ps[0]; sums[w][16 + lm] = ps[1]; }
    __syncthreads();
#pragma unroll
    for (int h = 0; h < 2; h++) {
        const int sl = h * 16 + lm;
        const int sg = s0 + sl;
        const float inv = 1.f / (sums[0][sl] + sums[1][sl] + sums[2][sl] + sums[3][sl]);
        const bool val2 = sg < SS;
#pragma unroll
        for (int r = 0; r < 4; r++) {
            const int k = w * 16 + quad * 4 + r;
            sap[(size_t)k * SP + sg] = val2 ? f2bf(e[h][r] * inv) : (unsigned short)0;
        }
    }
}

// ---------------------------------------------------------------------------
// K3: vlad GEMM.  v4: ALL 12 fragment loads hoisted above the MFMA block
// (sched_barrier fence) so they overlap; sasum tail loads batched.
// grid (NSPLIT, N) = 416 blocks; wave tile 32k x 64d.
// ---------------------------------------------------------------------------
__global__ __launch_bounds__(256)
void vlad_mfma(const unsigned short* __restrict__ xn, const unsigned short* __restrict__ sa,
               float* __restrict__ vladp, float* __restrict__ sasump)
{
    const int p = blockIdx.x;
    const int n = blockIdx.y;
    const int t = threadIdx.x;
    const int l = t & 63;
    const int w = t >> 6;
    const int kth = w & 1, nh = w >> 1;
    const int lm = l & 15, quad = l >> 4;

    const unsigned short* sap = sa + (size_t)n * KK * SP;
    const unsigned short* xnp = xn + (size_t)n * DD * SP;

    bf16x8 af[2][2], bfv[2][4];
#pragma unroll
    for (int st = 0; st < 2; st++) {
        const int sb = p * 64 + st * 32 + quad * 8;
#pragma unroll
        for (int j = 0; j < 2; j++)
            af[st][j] = *(const bf16x8*)&sap[(size_t)((kth * 2 + j) * 16 + lm) * SP + sb];
#pragma unroll
        for (int i = 0; i < 4; i++)
            bfv[st][i] = *(const bf16x8*)&xnp[(size_t)((nh * 4 + i) * 16 + lm) * SP + sb];
    }
    __builtin_amdgcn_sched_barrier(0);

    f32x4 acc[2][4];
#pragma unroll
    for (int j = 0; j < 2; j++)
#pragma unroll
        for (int i = 0; i < 4; i++) acc[j][i] = (f32x4){0.f, 0.f, 0.f, 0.f};

#pragma unroll
    for (int st = 0; st < 2; st++)
#pragma unroll
        for (int j = 0; j < 2; j++)
#pragma unroll
            for (int i = 0; i < 4; i++)
                acc[j][i] = __builtin_amdgcn_mfma_f32_16x16x32_bf16(af[st][j], bfv[st][i], acc[j][i], 0, 0, 0);

    float* vp = vladp + ((size_t)n * NSPLIT + p) * KD;
#pragma unroll
    for (int j = 0; j < 2; j++)
#pragma unroll
        for (int i = 0; i < 4; i++) {
            const int kq = (kth * 2 + j) * 4 + quad;          // k = kq*4 + r
            const int d  = (nh * 4 + i) * 16 + lm;
            *(f32x4*)&vp[(size_t)(kq * DD + d) * 4] = acc[j][i];
        }

    if (t < KK) {
        const unsigned short* rp = &sap[(size_t)t * SP + p * 64];
        bf16x8 vv[8];
#pragma unroll
        for (int c8 = 0; c8 < 8; c8++) vv[c8] = *(const bf16x8*)&rp[c8 * 8];
        float sm = 0.f;
#pragma unroll
        for (int c8 = 0; c8 < 8; c8++)
#pragma unroll
            for (int j = 0; j < 8; j++) sm += bf2f((unsigned short)vv[c8][j]);
        sasump[((size_t)n * NSPLIT + p) * KK + t] = sm;
    }
}

// ---------------------------------------------------------------------------
// K4: reduce NSPLIT partials.  v4: all 13 partial loads issued as a batch
// (register array + fence) before the dependent add chain; add order
// preserved (p ascending) -> bit-identical.
// ---------------------------------------------------------------------------
__global__ __launch_bounds__(256)
void vlad_finish(const float* __restrict__ vladp, const float* __restrict__ sasump,
                 const float* __restrict__ centroids, float* __restrict__ vladn)
{
    const int dg = blockIdx.x;
    const int n  = blockIdx.y;
    const int t  = threadIdx.x;
    const int kq = t & 15;
    const int d  = dg * 16 + (t >> 4);

    __shared__ float sas[KK];
    if (t < KK) {
        float pv[NSPLIT];
#pragma unroll
        for (int p = 0; p < NSPLIT; p++) pv[p] = sasump[((size_t)n * NSPLIT + p) * KK + t];
        float sm = 0.f;
#pragma unroll
        for (int p = 0; p < NSPLIT; p++) sm += pv[p];
        sas[t] = sm;
    }
    __syncthreads();

    f32x4 pr[NSPLIT];
#pragma unroll
    for (int p = 0; p < NSPLIT; p++)
        pr[p] = *(const f32x4*)&vladp[((size_t)n * NSPLIT + p) * KD + (size_t)(kq * DD + d) * 4];
    __builtin_amdgcn_sched_barrier(0);

    f32x4 v = (f32x4){0.f, 0.f, 0.f, 0.f};
#pragma unroll
    for (int p = 0; p < NSPLIT; p++) v += pr[p];
#pragma unroll
    for (int r = 0; r < 4; r++)
        v[r] -= centroids[(size_t)(kq * 4 + r) * DD + d] * sas[kq * 4 + r];

    float ssq = v[0] * v[0] + v[1] * v[1] + v[2] * v[2] + v[3] * v[3];
    ssq += __shfl_xor(ssq, 1, 64);
    ssq += __shfl_xor(ssq, 2, 64);
    ssq += __shfl_xor(ssq, 4, 64);
    ssq += __shfl_xor(ssq, 8, 64);               // full 16-kq group for this d
    const float scale = 1.f / fmaxf(sqrtf(ssq), 1e-12f);

    float* vo = vladn + (size_t)n * KD;
#pragma unroll
    for (int r = 0; r < 4; r++)
        vo[(size_t)(kq * 4 + r) * DD + d] = v[r] * scale;
}

// ---------------------------------------------------------------------------
// K5: projection via MFMA.  v4: explicit 2-stage software pipeline (named
// LA/LB load sets + fences) so each stage's 6 loads overlap the other
// stage's pack+MFMA.  Same pack/MFMA order -> bit-identical.
// ---------------------------------------------------------------------------
#define PROJ_ISSUE(L, KT) do {                                              \
    const int c_ = (KT) * 32;                                               \
    L[0] = *(const f32x4*)&wrow[c_];  L[1] = *(const f32x4*)&wrow[c_ + 4];  \
    L[2] = *(const f32x4*)&arow0[c_]; L[3] = *(const f32x4*)&arow0[c_ + 4]; \
    L[4] = *(const f32x4*)&arow1[c_]; L[5] = *(const f32x4*)&arow1[c_ + 4]; \
} while (0)

#define PROJ_STEP(L) do {                                                    \
    union { unsigned int u[4]; bf16x8 v; } ub, ua0, ua1;                     \
    ub.u[0]  = pk_bf16(L[0][0], L[0][1]); ub.u[1]  = pk_bf16(L[0][2], L[0][3]); \
    ub.u[2]  = pk_bf16(L[1][0], L[1][1]); ub.u[3]  = pk_bf16(L[1][2], L[1][3]); \
    ua0.u[0] = pk_bf16(L[2][0], L[2][1]); ua0.u[1] = pk_bf16(L[2][2], L[2][3]); \
    ua0.u[2] = pk_bf16(L[3][0], L[3][1]); ua0.u[3] = pk_bf16(L[3][2], L[3][3]); \
    ua1.u[0] = pk_bf16(L[4][0], L[4][1]); ua1.u[1] = pk_bf16(L[4][2], L[4][3]); \
    ua1.u[2] = pk_bf16(L[5][0], L[5][1]); ua1.u[3] = pk_bf16(L[5][2], L[5][3]); \
    acc[0] = __builtin_amdgcn_mfma_f32_16x16x32_bf16(ua0.v, ub.v, acc[0], 0, 0, 0); \
    acc[1] = __builtin_amdgcn_mfma_f32_16x16x32_bf16(ua1.v, ub.v, acc[1], 0, 0, 0); \
} while (0)

__global__ __launch_bounds__(256)
void proj_mfma(const float* __restrict__ vladn, const float* __restrict__ Wproj,
               float* __restrict__ outp)
{
    const int o0 = blockIdx.x * 64;
    const int c0 = blockIdx.y * (KD / PSPLIT);   // 256-wide c slice
    const int t  = threadIdx.x;
    const int l  = t & 63;
    const int w  = t >> 6;
    const int lm = l & 15, quad = l >> 4;
    const int o  = o0 + w * 16 + lm;

    const float* wrow  = &Wproj[(size_t)o * KD + c0 + quad * 8];
    const float* arow0 = &vladn[(size_t)lm * KD + c0 + quad * 8];
    const float* arow1 = &vladn[(size_t)(16 + lm) * KD + c0 + quad * 8];

    f32x4 acc[2];
    acc[0] = (f32x4){0.f, 0.f, 0.f, 0.f};
    acc[1] = (f32x4){0.f, 0.f, 0.f, 0.f};

    f32x4 LA[6], LB[6];
    PROJ_ISSUE(LA, 0);
#pragma unroll
    for (int kt = 0; kt < 8; kt += 2) {
        PROJ_ISSUE(LB, kt + 1);
        __builtin_amdgcn_sched_barrier(0);
        PROJ_STEP(LA);
        if (kt + 2 < 8) PROJ_ISSUE(LA, kt + 2);
        __builtin_amdgcn_sched_barrier(0);
        PROJ_STEP(LB);
    }

    // C layout: col lm -> o (matches B), row quad*4+r -> n = a*16+quad*4+r
#pragma unroll
    for (int a = 0; a < 2; a++)
#pragma unroll
        for (int r = 0; r < 4; r++) {
            const int nn = a * 16 + quad * 4 + r;
            outp[((size_t)blockIdx.y * NB + nn) * OUTD + o] = acc[a][r];
        }
}

// ---------------------------------------------------------------------------
// K6: sum projection partials + bproj, final L2 norm over OUT, write d_out.
// v4: partial loads batched 16-at-a-time (register array + fence); add order
// preserved (p ascending) -> bit-identical.
// ---------------------------------------------------------------------------
__global__ __launch_bounds__(256)
void final_norm_kernel(const float* __restrict__ outp, const float* __restrict__ bproj,
                       float* __restrict__ out)
{
    const int n = blockIdx.x;
    const int t = threadIdx.x;
    const int o4 = t * 4;

    float4 a = *(const float4*)&bproj[o4];
    f32x4 pr[16];
#pragma unroll
    for (int b = 0; b < 2; b++) {
#pragma unroll
        for (int i = 0; i < 16; i++)
            pr[i] = *(const f32x4*)&outp[((size_t)(b * 16 + i) * NB + n) * OUTD + o4];
        __builtin_amdgcn_sched_barrier(0);
#pragma unroll
        for (int i = 0; i < 16; i++) {
            a.x += pr[i][0]; a.y += pr[i][1]; a.z += pr[i][2]; a.w += pr[i][3];
        }
    }
    float ssp = a.x * a.x + a.y * a.y + a.z * a.z + a.w * a.w;
#pragma unroll
    for (int off = 32; off > 0; off >>= 1) ssp += __shfl_down(ssp, off, 64);
    __shared__ float rs[4];
    if ((t & 63) == 0) rs[t >> 6] = ssp;
    __syncthreads();
    const float total = rs[0] + rs[1] + rs[2] + rs[3];
    const float scale = 1.f / fmaxf(sqrtf(total), 1e-12f);
    float4 o;
    o.x = a.x * scale; o.y = a.y * scale; o.z = a.z * scale; o.w = a.w * scale;
    *(float4*)&out[(size_t)n * OUTD + o4] = o;
}

// ---------------------------------------------------------------------------
extern "C" void kernel_launch(void* const* d_in, const int* in_sizes, int n_in,
                              void* d_out, int out_size, void* d_ws, size_t ws_size,
                              hipStream_t stream)
{
    const float* x         = (const float*)d_in[0];
    const float* Wpool     = (const float*)d_in[1];
    const float* bpool     = (const float*)d_in[2];
    const float* Wconv     = (const float*)d_in[3];
    const float* bconv     = (const float*)d_in[4];
    const float* centroids = (const float*)d_in[5];
    const float* Wproj     = (const float*)d_in[6];
    const float* bproj     = (const float*)d_in[7];
    float* out = (float*)d_out;
    char*  wsb = (char*)d_ws;

    unsigned short* xn     = (unsigned short*)(wsb + OFF_XN);
    unsigned short* sa     = (unsigned short*)(wsb + OFF_SA);
    unsigned short* Wpk    = (unsigned short*)(wsb + OFF_WPK);
    unsigned short* Wck    = (unsigned short*)(wsb + OFF_WCK);
    float*          vladp  = (float*)(wsb + OFF_VLADP);
    float*          sasump = (float*)(wsb + OFF_SASUM);
    float*          vladn  = (float*)(wsb + OFF_VLADN);
    float*          outp   = (float*)(wsb + OFF_OUTP);

    pack_weights<<<dim3(9), 256, 0, stream>>>(Wpool, Wconv, Wpk, Wck);
    pool_norm_assign<<<dim3(26, NB), 256, 0, stream>>>(x, Wpk, bpool, Wck, bconv, xn, sa);
    vlad_mfma<<<dim3(NSPLIT, NB), 256, 0, stream>>>(xn, sa, vladp, sasump);
    vlad_finish<<<dim3(DD / 16, NB), 256, 0, stream>>>(vladp, sasump, centroids, vladn);
    proj_mfma<<<dim3(OUTD / 64, PSPLIT), 256, 0, stream>>>(vladn, Wproj, outp);
    final_norm_kernel<<<dim3(NB), 256, 0, stream>>>(outp, bproj, out);
}

// Round 4
// 221.999 us; speedup vs baseline: 1.0611x; 1.0309x over previous
//
#include <hip/hip_runtime.h>
#include <math.h>

#define NB 32
#define CC 1024
#define SS 784
#define SP 832           // padded S (52*16); pad region of sa is zeroed
#define DD 128
#define KK 64
#define OUTD 1024
#define KD 8192          // K*D
#define NSPLIT 13        // vlad s-splits (64 s each)
#define PSPLIT 32        // split-K for projection (8192 = 32*256)

// workspace layout (BYTE offsets)  -- total ~29.5 MB (< 30.9 MB known-good)
#define OFF_XN    0                                   // bf16 (N,D,SP)
#define OFF_SA    (OFF_XN + NB*DD*SP*2)               // bf16 (N,K,SP)
#define OFF_WPK   (OFF_SA + NB*KK*SP*2)               // bf16 Wpool frag-packed (32*8*64*8)
#define OFF_WCK   (OFF_WPK + 32*8*64*8*2)             // bf16 Wconv frag-packed (16*64*8)
#define OFF_VLADP (OFF_WCK + 16*64*8*2)               // f32 (N,NSPLIT,KD) packed C-layout
#define OFF_SASUM (OFF_VLADP + NB*NSPLIT*KD*4)        // f32 (N,NSPLIT,K)
#define OFF_VLADN (OFF_SASUM + NB*NSPLIT*KK*4)        // f32 (N,KD)
#define OFF_OUTP  (OFF_VLADN + NB*KD*4)               // f32 (PSPLIT,N,OUT)

typedef __attribute__((ext_vector_type(8))) short bf16x8;   // 8 bf16 = 4 VGPRs
typedef __attribute__((ext_vector_type(4))) float f32x4;
typedef __attribute__((ext_vector_type(4))) unsigned int u32x4;

__device__ __forceinline__ unsigned int pk_bf16(float a, float b) {
    unsigned int ua = __builtin_bit_cast(unsigned int, a);
    unsigned int ub = __builtin_bit_cast(unsigned int, b);
    ua += 0x7FFFu + ((ua >> 16) & 1u);
    ub += 0x7FFFu + ((ub >> 16) & 1u);
    return (ua >> 16) | (ub & 0xFFFF0000u);
}
__device__ __forceinline__ unsigned short f2bf(float a) {
    unsigned int ua = __builtin_bit_cast(unsigned int, a);
    ua += 0x7FFFu + ((ua >> 16) & 1u);
    return (unsigned short)(ua >> 16);
}
__device__ __forceinline__ float bf2f(unsigned short u) {
    unsigned int v = ((unsigned int)u) << 16;
    return __builtin_bit_cast(float, v);
}

// ---------------------------------------------------------------------------
// c-permutation shared by pack_weights and pool staging:
// cb (0..127 = c-block of 8), elem j (0..7):
//   c = (cb>>5)*256 + ((cb>>3)&3)*64 + (cb&7) + 8*j
// GEMM contraction order over c is free as long as Wpk uses the SAME perm.
// ---------------------------------------------------------------------------

// ---------------------------------------------------------------------------
// K1 v5: pack Wpool/Wconv into MFMA A-fragment order.  Grid (9, 8): the old
// per-block unroll loop is now blockIdx.y (R2/R3 ran 9 blocks = 2304 threads
// on a 256-CU chip -> pure exposed latency).
// ---------------------------------------------------------------------------
__global__ __launch_bounds__(256)
void pack_weights(const float* __restrict__ Wpool, const float* __restrict__ Wconv,
                  unsigned short* __restrict__ Wpk, unsigned short* __restrict__ Wck)
{
    const int b = blockIdx.x;
    const int t = threadIdx.x;
    if (b < 8) {
        const int i = blockIdx.y;              // 0..7
        const int id = t + 256 * i;            // 0..2047
        const int ktl = id >> 9;               // 0..3
        const int mt  = (id >> 6) & 7;
        const int l   = id & 63;
        const int lm = l & 15, quad = l >> 4;
        const int kt = b * 4 + ktl;
        const int d = mt * 16 + lm;
        const int cb = kt * 4 + quad;          // 0..127
        const int base_c = (cb >> 5) * 256 + ((cb >> 3) & 3) * 64 + (cb & 7);
        float v[8];
#pragma unroll
        for (int j = 0; j < 8; j++) v[j] = Wpool[(size_t)d * CC + base_c + 8 * j];
        unsigned int* dst = (unsigned int*)&Wpk[(size_t)((kt * 8 + mt) * 64 + l) * 8];
        dst[0] = pk_bf16(v[0], v[1]); dst[1] = pk_bf16(v[2], v[3]);
        dst[2] = pk_bf16(v[4], v[5]); dst[3] = pk_bf16(v[6], v[7]);
    } else if (blockIdx.y < 4) {
        const int i = blockIdx.y;              // 0..3
        const int id = t + 256 * i;            // 0..1023
        const int tile = id >> 6;
        const int l = id & 63;
        const int lm = l & 15, quad = l >> 4;
        const int k = (tile >> 2) * 16 + lm;
        const int d = (tile & 3) * 32 + quad * 8;
        const float4 v0 = *(const float4*)&Wconv[(size_t)k * DD + d];
        const float4 v1 = *(const float4*)&Wconv[(size_t)k * DD + d + 4];
        unsigned int* dst = (unsigned int*)&Wck[(size_t)(tile * 64 + l) * 8];
        dst[0] = pk_bf16(v0.x, v0.y); dst[1] = pk_bf16(v0.z, v0.w);
        dst[2] = pk_bf16(v1.x, v1.y); dst[3] = pk_bf16(v1.z, v1.w);
    }
}

// ---------------------------------------------------------------------------
// K2 v5: same math/schedule as v4 (bit-identical output).  LDS cut 41 KB ->
// 33.25 KB by aliasing: xnT reuses Bst[0] (last Bst[0] read completes two
// barriers before xnT's first write) and sums aliases red (all red reads
// precede the barrier before any sums write).  __launch_bounds__(256,4):
// 4 blocks/CU = 16 waves/CU, grid 832 <= 1024 slots -> single round.
// ---------------------------------------------------------------------------
__global__ __launch_bounds__(256, 4)
void pool_norm_assign(const float* __restrict__ x, const unsigned short* __restrict__ Wpk,
                      const float* __restrict__ bpool, const unsigned short* __restrict__ Wck,
                      const float* __restrict__ bconv,
                      unsigned short* __restrict__ xn, unsigned short* __restrict__ sa)
{
    const int n  = blockIdx.y;
    const int s0 = blockIdx.x * 32;
    const int t  = threadIdx.x;
    const int l  = t & 63;
    const int w  = t >> 6;       // wave 0..3
    const int lm = l & 15;
    const int quad = l >> 4;

    // 33.25 KB total: Bst0 (16 KB) | Bst1 (16 KB) | red/sums (1.25 KB pad-incl)
    __shared__ alignas(16) unsigned char smem[2 * 32 * 32 * 8 * 2 + 4 * 32 * 4];
    unsigned short* Bst0 = (unsigned short*)smem;
    unsigned short* Bst1 = Bst0 + 32 * 32 * 8;
    unsigned short* xnT  = Bst0;                      // alias (see header)
    float* red  = (float*)(smem + 2 * 32 * 32 * 8 * 2);  // [4][32]
    float* sums = red;                                   // alias (see header)

    unsigned short* xnp = xn + (size_t)n * DD * SP;
    unsigned short* sap = sa + (size_t)n * KK * SP;

    if (s0 >= SS) {
        // pure-pad tile (s0 = 800): zero xn and sa for s 800..831, exit.
        const u32x4 z = (u32x4){0u, 0u, 0u, 0u};
#pragma unroll
        for (int pp = 0; pp < 2; pp++) {
            const int idx = t + 256 * pp;
            *(u32x4*)&xnp[(size_t)(idx >> 2) * SP + s0 + (idx & 3) * 8] = z;
        }
        *(u32x4*)&sap[(size_t)(t >> 2) * SP + s0 + (t & 3) * 8] = z;
        return;
    }

    const int r0 = (l >> 3) & 7;   // row-in-group 0..7
    const int se = l & 7;          // 16B s-chunk 0..7
    // chunk-aligned clamp for the mixed tile 24 (s 784..799 OOB -> reload
    // an in-bounds chunk; values garbage-but-finite, neutralized by sa=0)
    int sc = s0 + se * 4;
    if (sc + 4 > SS) sc = s0 + (se & 3) * 4;
    const float* xw = x + (size_t)n * CC * SS + sc;
    const int crow0 = w * 64 + r0;                 // + q*256 + j*8 = global c row

    // ---- prologue: issue quarter-0 x loads + Wpk depth-4 prefetch, THEN pack
    f32x4 g[8];
#pragma unroll
    for (int j = 0; j < 8; j++)
        g[j] = *(const f32x4*)&xw[(size_t)(crow0 + j * 8) * SS];

    bf16x8 abuf[4][2];  // prefetch depth 4: slot kt&3
#pragma unroll
    for (int p = 0; p < 4; p++)
#pragma unroll
        for (int i = 0; i < 2; i++)
            abuf[p][i] = *(const bf16x8*)&Wpk[(size_t)((p * 8 + w * 2 + i) * 64 + l) * 8];

    __builtin_amdgcn_sched_barrier(0);

#pragma unroll
    for (int ss = 0; ss < 4; ss++) {
        const int s = se * 4 + ss;
        const int sig = s ^ ((s >> 3) & 3);
        unsigned int* dst = (unsigned int*)&Bst0[(size_t)((w * 8 + r0) * 32 + sig) * 8];
        dst[0] = pk_bf16(g[0][ss], g[1][ss]); dst[1] = pk_bf16(g[2][ss], g[3][ss]);
        dst[2] = pk_bf16(g[4][ss], g[5][ss]); dst[3] = pk_bf16(g[6][ss], g[7][ss]);
    }
    __syncthreads();

    f32x4 acc[2][2];   // [i=d-tile][h=s-sub]
#pragma unroll
    for (int i = 0; i < 2; i++)
#pragma unroll
        for (int h = 0; h < 2; h++) acc[i][h] = (f32x4){0.f, 0.f, 0.f, 0.f};

    for (int q = 0; q < 4; ++q) {
        // issue next-quarter x loads (consumed only after this K-loop)
        if (q < 3) {
#pragma unroll
            for (int j = 0; j < 8; j++)
                g[j] = *(const f32x4*)&xw[(size_t)((q + 1) * 256 + crow0 + j * 8) * SS];
        }
        __builtin_amdgcn_sched_barrier(0);   // loads stay ABOVE the K-loop
        const unsigned short* Bq = (q & 1) ? Bst1 : Bst0;
#pragma unroll
        for (int ktq = 0; ktq < 8; ++ktq) {
            const int kt = q * 8 + ktq;
            const bf16x8 a0 = abuf[ktq & 3][0], a1 = abuf[ktq & 3][1];
            if (kt < 28) {
#pragma unroll
                for (int i = 0; i < 2; i++)
                    abuf[ktq & 3][i] = *(const bf16x8*)&Wpk[(size_t)(((kt + 4) * 8 + w * 2 + i) * 64 + l) * 8];
            }
#pragma unroll
            for (int h = 0; h < 2; h++) {
                const int s = h * 16 + lm;
                const int sig = s ^ ((s >> 3) & 3);
                const bf16x8 bf = *(const bf16x8*)&Bq[(size_t)((ktq * 4 + quad) * 32 + sig) * 8];
                acc[0][h] = __builtin_amdgcn_mfma_f32_16x16x32_bf16(a0, bf, acc[0][h], 0, 0, 0);
                acc[1][h] = __builtin_amdgcn_mfma_f32_16x16x32_bf16(a1, bf, acc[1][h], 0, 0, 0);
            }
        }
        __builtin_amdgcn_sched_barrier(0);   // packs stay BELOW the K-loop
        if (q < 3) {
            unsigned short* Bn = ((q + 1) & 1) ? Bst1 : Bst0;
#pragma unroll
            for (int ss = 0; ss < 4; ss++) {
                const int s = se * 4 + ss;
                const int sig = s ^ ((s >> 3) & 3);
                unsigned int* dst = (unsigned int*)&Bn[(size_t)((w * 8 + r0) * 32 + sig) * 8];
                dst[0] = pk_bf16(g[0][ss], g[1][ss]); dst[1] = pk_bf16(g[2][ss], g[3][ss]);
                dst[2] = pk_bf16(g[4][ss], g[5][ss]); dst[3] = pk_bf16(g[6][ss], g[7][ss]);
            }
        }
        __syncthreads();
    }

    // ---- PHASE 3a: bias + L2-norm over d.  C: d=(2w+i)*16+quad*4+r, s=h*16+lm
    float vals[2][2][4];
    float ssq[2] = {0.f, 0.f};
#pragma unroll
    for (int i = 0; i < 2; i++)
#pragma unroll
        for (int h = 0; h < 2; h++)
#pragma unroll
            for (int r = 0; r < 4; r++) {
                const int d = (w * 2 + i) * 16 + quad * 4 + r;
                const float v = acc[i][h][r] + bpool[d];
                vals[i][h][r] = v; ssq[h] += v * v;
            }
#pragma unroll
    for (int h = 0; h < 2; h++) {
        ssq[h] += __shfl_xor(ssq[h], 16, 64);
        ssq[h] += __shfl_xor(ssq[h], 32, 64);
    }
    if (quad == 0) { red[w * 32 + lm] = ssq[0]; red[w * 32 + 16 + lm] = ssq[1]; }
    __syncthreads();
    float scale[2];
#pragma unroll
    for (int h = 0; h < 2; h++) {
        const int sl = h * 16 + lm;
        scale[h] = 1.f / fmaxf(sqrtf(red[0 * 32 + sl] + red[1 * 32 + sl] + red[2 * 32 + sl] + red[3 * 32 + sl]), 1e-12f);
    }
    // red reads complete here for all threads before the next barrier;
    // xnT (aliasing Bst0, last read 2 barriers ago) is written now.
#pragma unroll
    for (int i = 0; i < 2; i++)
#pragma unroll
        for (int h = 0; h < 2; h++)
#pragma unroll
            for (int r = 0; r < 4; r++) {
                const int d = (w * 2 + i) * 16 + quad * 4 + r;
                const int sg = s0 + h * 16 + lm;
                const float v = vals[i][h][r] * scale[h];
                xnp[(size_t)d * SP + sg] = f2bf(v);
                xnT[(size_t)(((d >> 3) * 32) + h * 16 + lm) * 8 + (d & 7)] = f2bf(v);
            }
    __syncthreads();

    // ---- PHASE 3b: assign GEMM (64k x 32s), wave w -> k-tile w
    f32x4 acc2[2];
    acc2[0] = (f32x4){0.f, 0.f, 0.f, 0.f};
    acc2[1] = (f32x4){0.f, 0.f, 0.f, 0.f};
#pragma unroll
    for (int dsv = 0; dsv < 4; dsv++) {
        const bf16x8 afrag = *(const bf16x8*)&Wck[(size_t)((w * 4 + dsv) * 64 + l) * 8];
#pragma unroll
        for (int h = 0; h < 2; h++) {
            const bf16x8 bfrag = *(const bf16x8*)&xnT[(size_t)((dsv * 4 + quad) * 32 + h * 16 + lm) * 8];
            acc2[h] = __builtin_amdgcn_mfma_f32_16x16x32_bf16(afrag, bfrag, acc2[h], 0, 0, 0);
        }
    }
    // softmax over k (|logits| small since x-hat unit-norm: no max-sub needed)
    float e[2][4]; float ps[2] = {0.f, 0.f};
#pragma unroll
    for (int h = 0; h < 2; h++)
#pragma unroll
        for (int r = 0; r < 4; r++) {
            const int k = w * 16 + quad * 4 + r;
            e[h][r] = expf(acc2[h][r] + bconv[k]);
            ps[h] += e[h][r];
        }
#pragma unroll
    for (int h = 0; h < 2; h++) {
        ps[h] += __shfl_xor(ps[h], 16, 64);
        ps[h] += __shfl_xor(ps[h], 32, 64);
    }
    if (quad == 0) { sums[w * 32 + lm] = ps[0]; sums[w * 32 + 16 + lm] = ps[1]; }
    __syncthreads();
#pragma unroll
    for (int h = 0; h < 2; h++) {
        const int sl = h * 16 + lm;
        const int sg = s0 + sl;
        const float inv = 1.f / (sums[0 * 32 + sl] + sums[1 * 32 + sl] + sums[2 * 32 + sl] + sums[3 * 32 + sl]);
        const bool val2 = sg < SS;
#pragma unroll
        for (int r = 0; r < 4; r++) {
            const int k = w * 16 + quad * 4 + r;
            sap[(size_t)k * SP + sg] = val2 ? f2bf(e[h][r] * inv) : (unsigned short)0;
        }
    }
}

// ---------------------------------------------------------------------------
// K3: vlad GEMM.  v4: ALL 12 fragment loads hoisted above the MFMA block
// (sched_barrier fence) so they overlap; sasum tail loads batched.
// grid (NSPLIT, N) = 416 blocks; wave tile 32k x 64d.
// ---------------------------------------------------------------------------
__global__ __launch_bounds__(256)
void vlad_mfma(const unsigned short* __restrict__ xn, const unsigned short* __restrict__ sa,
               float* __restrict__ vladp, float* __restrict__ sasump)
{
    const int p = blockIdx.x;
    const int n = blockIdx.y;
    const int t = threadIdx.x;
    const int l = t & 63;
    const int w = t >> 6;
    const int kth = w & 1, nh = w >> 1;
    const int lm = l & 15, quad = l >> 4;

    const unsigned short* sap = sa + (size_t)n * KK * SP;
    const unsigned short* xnp = xn + (size_t)n * DD * SP;

    bf16x8 af[2][2], bfv[2][4];
#pragma unroll
    for (int st = 0; st < 2; st++) {
        const int sb = p * 64 + st * 32 + quad * 8;
#pragma unroll
        for (int j = 0; j < 2; j++)
            af[st][j] = *(const bf16x8*)&sap[(size_t)((kth * 2 + j) * 16 + lm) * SP + sb];
#pragma unroll
        for (int i = 0; i < 4; i++)
            bfv[st][i] = *(const bf16x8*)&xnp[(size_t)((nh * 4 + i) * 16 + lm) * SP + sb];
    }
    __builtin_amdgcn_sched_barrier(0);

    f32x4 acc[2][4];
#pragma unroll
    for (int j = 0; j < 2; j++)
#pragma unroll
        for (int i = 0; i < 4; i++) acc[j][i] = (f32x4){0.f, 0.f, 0.f, 0.f};

#pragma unroll
    for (int st = 0; st < 2; st++)
#pragma unroll
        for (int j = 0; j < 2; j++)
#pragma unroll
            for (int i = 0; i < 4; i++)
                acc[j][i] = __builtin_amdgcn_mfma_f32_16x16x32_bf16(af[st][j], bfv[st][i], acc[j][i], 0, 0, 0);

    float* vp = vladp + ((size_t)n * NSPLIT + p) * KD;
#pragma unroll
    for (int j = 0; j < 2; j++)
#pragma unroll
        for (int i = 0; i < 4; i++) {
            const int kq = (kth * 2 + j) * 4 + quad;          // k = kq*4 + r
            const int d  = (nh * 4 + i) * 16 + lm;
            *(f32x4*)&vp[(size_t)(kq * DD + d) * 4] = acc[j][i];
        }

    if (t < KK) {
        const unsigned short* rp = &sap[(size_t)t * SP + p * 64];
        bf16x8 vv[8];
#pragma unroll
        for (int c8 = 0; c8 < 8; c8++) vv[c8] = *(const bf16x8*)&rp[c8 * 8];
        float sm = 0.f;
#pragma unroll
        for (int c8 = 0; c8 < 8; c8++)
#pragma unroll
            for (int j = 0; j < 8; j++) sm += bf2f((unsigned short)vv[c8][j]);
        sasump[((size_t)n * NSPLIT + p) * KK + t] = sm;
    }
}

// ---------------------------------------------------------------------------
// K4: reduce NSPLIT partials.  v4: all 13 partial loads issued as a batch
// (register array + fence) before the dependent add chain; add order
// preserved (p ascending) -> bit-identical.
// ---------------------------------------------------------------------------
__global__ __launch_bounds__(256)
void vlad_finish(const float* __restrict__ vladp, const float* __restrict__ sasump,
                 const float* __restrict__ centroids, float* __restrict__ vladn)
{
    const int dg = blockIdx.x;
    const int n  = blockIdx.y;
    const int t  = threadIdx.x;
    const int kq = t & 15;
    const int d  = dg * 16 + (t >> 4);

    __shared__ float sas[KK];
    if (t < KK) {
        float pv[NSPLIT];
#pragma unroll
        for (int p = 0; p < NSPLIT; p++) pv[p] = sasump[((size_t)n * NSPLIT + p) * KK + t];
        float sm = 0.f;
#pragma unroll
        for (int p = 0; p < NSPLIT; p++) sm += pv[p];
        sas[t] = sm;
    }
    __syncthreads();

    f32x4 pr[NSPLIT];
#pragma unroll
    for (int p = 0; p < NSPLIT; p++)
        pr[p] = *(const f32x4*)&vladp[((size_t)n * NSPLIT + p) * KD + (size_t)(kq * DD + d) * 4];
    __builtin_amdgcn_sched_barrier(0);

    f32x4 v = (f32x4){0.f, 0.f, 0.f, 0.f};
#pragma unroll
    for (int p = 0; p < NSPLIT; p++) v += pr[p];
#pragma unroll
    for (int r = 0; r < 4; r++)
        v[r] -= centroids[(size_t)(kq * 4 + r) * DD + d] * sas[kq * 4 + r];

    float ssq = v[0] * v[0] + v[1] * v[1] + v[2] * v[2] + v[3] * v[3];
    ssq += __shfl_xor(ssq, 1, 64);
    ssq += __shfl_xor(ssq, 2, 64);
    ssq += __shfl_xor(ssq, 4, 64);
    ssq += __shfl_xor(ssq, 8, 64);               // full 16-kq group for this d
    const float scale = 1.f / fmaxf(sqrtf(ssq), 1e-12f);

    float* vo = vladn + (size_t)n * KD;
#pragma unroll
    for (int r = 0; r < 4; r++)
        vo[(size_t)(kq * 4 + r) * DD + d] = v[r] * scale;
}

// ---------------------------------------------------------------------------
// K5: projection via MFMA.  v4: explicit 2-stage software pipeline (named
// LA/LB load sets + fences) so each stage's 6 loads overlap the other
// stage's pack+MFMA.  Same pack/MFMA order -> bit-identical.
// ---------------------------------------------------------------------------
#define PROJ_ISSUE(L, KT) do {                                              \
    const int c_ = (KT) * 32;                                               \
    L[0] = *(const f32x4*)&wrow[c_];  L[1] = *(const f32x4*)&wrow[c_ + 4];  \
    L[2] = *(const f32x4*)&arow0[c_]; L[3] = *(const f32x4*)&arow0[c_ + 4]; \
    L[4] = *(const f32x4*)&arow1[c_]; L[5] = *(const f32x4*)&arow1[c_ + 4]; \
} while (0)

#define PROJ_STEP(L) do {                                                    \
    union { unsigned int u[4]; bf16x8 v; } ub, ua0, ua1;                     \
    ub.u[0]  = pk_bf16(L[0][0], L[0][1]); ub.u[1]  = pk_bf16(L[0][2], L[0][3]); \
    ub.u[2]  = pk_bf16(L[1][0], L[1][1]); ub.u[3]  = pk_bf16(L[1][2], L[1][3]); \
    ua0.u[0] = pk_bf16(L[2][0], L[2][1]); ua0.u[1] = pk_bf16(L[2][2], L[2][3]); \
    ua0.u[2] = pk_bf16(L[3][0], L[3][1]); ua0.u[3] = pk_bf16(L[3][2], L[3][3]); \
    ua1.u[0] = pk_bf16(L[4][0], L[4][1]); ua1.u[1] = pk_bf16(L[4][2], L[4][3]); \
    ua1.u[2] = pk_bf16(L[5][0], L[5][1]); ua1.u[3] = pk_bf16(L[5][2], L[5][3]); \
    acc[0] = __builtin_amdgcn_mfma_f32_16x16x32_bf16(ua0.v, ub.v, acc[0], 0, 0, 0); \
    acc[1] = __builtin_amdgcn_mfma_f32_16x16x32_bf16(ua1.v, ub.v, acc[1], 0, 0, 0); \
} while (0)

__global__ __launch_bounds__(256)
void proj_mfma(const float* __restrict__ vladn, const float* __restrict__ Wproj,
               float* __restrict__ outp)
{
    const int o0 = blockIdx.x * 64;
    const int c0 = blockIdx.y * (KD / PSPLIT);   // 256-wide c slice
    const int t  = threadIdx.x;
    const int l  = t & 63;
    const int w  = t >> 6;
    const int lm = l & 15, quad = l >> 4;
    const int o  = o0 + w * 16 + lm;

    const float* wrow  = &Wproj[(size_t)o * KD + c0 + quad * 8];
    const float* arow0 = &vladn[(size_t)lm * KD + c0 + quad * 8];
    const float* arow1 = &vladn[(size_t)(16 + lm) * KD + c0 + quad * 8];

    f32x4 acc[2];
    acc[0] = (f32x4){0.f, 0.f, 0.f, 0.f};
    acc[1] = (f32x4){0.f, 0.f, 0.f, 0.f};

    f32x4 LA[6], LB[6];
    PROJ_ISSUE(LA, 0);
#pragma unroll
    for (int kt = 0; kt < 8; kt += 2) {
        PROJ_ISSUE(LB, kt + 1);
        __builtin_amdgcn_sched_barrier(0);
        PROJ_STEP(LA);
        if (kt + 2 < 8) PROJ_ISSUE(LA, kt + 2);
        __builtin_amdgcn_sched_barrier(0);
        PROJ_STEP(LB);
    }

    // C layout: col lm -> o (matches B), row quad*4+r -> n = a*16+quad*4+r
#pragma unroll
    for (int a = 0; a < 2; a++)
#pragma unroll
        for (int r = 0; r < 4; r++) {
            const int nn = a * 16 + quad * 4 + r;
            outp[((size_t)blockIdx.y * NB + nn) * OUTD + o] = acc[a][r];
        }
}

// ---------------------------------------------------------------------------
// K6: sum projection partials + bproj, final L2 norm over OUT, write d_out.
// v4: partial loads batched 16-at-a-time (register array + fence); add order
// preserved (p ascending) -> bit-identical.
// ---------------------------------------------------------------------------
__global__ __launch_bounds__(256)
void final_norm_kernel(const float* __restrict__ outp, const float* __restrict__ bproj,
                       float* __restrict__ out)
{
    const int n = blockIdx.x;
    const int t = threadIdx.x;
    const int o4 = t * 4;

    float4 a = *(const float4*)&bproj[o4];
    f32x4 pr[16];
#pragma unroll
    for (int b = 0; b < 2; b++) {
#pragma unroll
        for (int i = 0; i < 16; i++)
            pr[i] = *(const f32x4*)&outp[((size_t)(b * 16 + i) * NB + n) * OUTD + o4];
        __builtin_amdgcn_sched_barrier(0);
#pragma unroll
        for (int i = 0; i < 16; i++) {
            a.x += pr[i][0]; a.y += pr[i][1]; a.z += pr[i][2]; a.w += pr[i][3];
        }
    }
    float ssp = a.x * a.x + a.y * a.y + a.z * a.z + a.w * a.w;
#pragma unroll
    for (int off = 32; off > 0; off >>= 1) ssp += __shfl_down(ssp, off, 64);
    __shared__ float rs[4];
    if ((t & 63) == 0) rs[t >> 6] = ssp;
    __syncthreads();
    const float total = rs[0] + rs[1] + rs[2] + rs[3];
    const float scale = 1.f / fmaxf(sqrtf(total), 1e-12f);
    float4 o;
    o.x = a.x * scale; o.y = a.y * scale; o.z = a.z * scale; o.w = a.w * scale;
    *(float4*)&out[(size_t)n * OUTD + o4] = o;
}

// ---------------------------------------------------------------------------
extern "C" void kernel_launch(void* const* d_in, const int* in_sizes, int n_in,
                              void* d_out, int out_size, void* d_ws, size_t ws_size,
                              hipStream_t stream)
{
    const float* x         = (const float*)d_in[0];
    const float* Wpool     = (const float*)d_in[1];
    const float* bpool     = (const float*)d_in[2];
    const float* Wconv     = (const float*)d_in[3];
    const float* bconv     = (const float*)d_in[4];
    const float* centroids = (const float*)d_in[5];
    const float* Wproj     = (const float*)d_in[6];
    const float* bproj     = (const float*)d_in[7];
    float* out = (float*)d_out;
    char*  wsb = (char*)d_ws;

    unsigned short* xn     = (unsigned short*)(wsb + OFF_XN);
    unsigned short* sa     = (unsigned short*)(wsb + OFF_SA);
    unsigned short* Wpk    = (unsigned short*)(wsb + OFF_WPK);
    unsigned short* Wck    = (unsigned short*)(wsb + OFF_WCK);
    float*          vladp  = (float*)(wsb + OFF_VLADP);
    float*          sasump = (float*)(wsb + OFF_SASUM);
    float*          vladn  = (float*)(wsb + OFF_VLADN);
    float*          outp   = (float*)(wsb + OFF_OUTP);

    pack_weights<<<dim3(9, 8), 256, 0, stream>>>(Wpool, Wconv, Wpk, Wck);
    pool_norm_assign<<<dim3(26, NB), 256, 0, stream>>>(x, Wpk, bpool, Wck, bconv, xn, sa);
    vlad_mfma<<<dim3(NSPLIT, NB), 256, 0, stream>>>(xn, sa, vladp, sasump);
    vlad_finish<<<dim3(DD / 16, NB), 256, 0, stream>>>(vladp, sasump, centroids, vladn);
    proj_mfma<<<dim3(OUTD / 64, PSPLIT), 256, 0, stream>>>(vladn, Wproj, outp);
    final_norm_kernel<<<dim3(NB), 256, 0, stream>>>(outp, bproj, out);
}

// Round 7
// 213.721 us; speedup vs baseline: 1.1022x; 1.0387x over previous
//
#include <hip/hip_runtime.h>
#include <math.h>

#define NB 32
#define CC 1024
#define SS 784
#define SP 832           // padded S (52*16); pad region of sa is zeroed
#define DD 128
#define KK 64
#define OUTD 1024
#define KD 8192          // K*D
#define PSPLIT 16        // split-K for projection (8192 = 16*512)

// workspace layout (BYTE offsets)  -- total ~13.6 MB
#define OFF_XN    0                                   // bf16 (N,D,SP)
#define OFF_SA    (OFF_XN + NB*DD*SP*2)               // bf16 (N,K,SP)
#define OFF_WPK   (OFF_SA + NB*KK*SP*2)               // bf16 Wpool frag-packed (32*8*64*8)
#define OFF_WCK   (OFF_WPK + 32*8*64*8*2)             // bf16 Wconv frag-packed (16*64*8)
#define OFF_VLADN (OFF_WCK + 16*64*8*2)               // f32 (N,KD)
#define OFF_OUTP  (OFF_VLADN + NB*KD*4)               // f32 (PSPLIT,N,OUT)

typedef __attribute__((ext_vector_type(8))) short bf16x8;   // 8 bf16 = 4 VGPRs
typedef __attribute__((ext_vector_type(4))) float f32x4;
typedef __attribute__((ext_vector_type(4))) unsigned int u32x4;

__device__ __forceinline__ unsigned int pk_bf16(float a, float b) {
    unsigned int ua = __builtin_bit_cast(unsigned int, a);
    unsigned int ub = __builtin_bit_cast(unsigned int, b);
    ua += 0x7FFFu + ((ua >> 16) & 1u);
    ub += 0x7FFFu + ((ub >> 16) & 1u);
    return (ua >> 16) | (ub & 0xFFFF0000u);
}
__device__ __forceinline__ unsigned short f2bf(float a) {
    unsigned int ua = __builtin_bit_cast(unsigned int, a);
    ua += 0x7FFFu + ((ua >> 16) & 1u);
    return (unsigned short)(ua >> 16);
}
__device__ __forceinline__ float bf2f(unsigned short u) {
    unsigned int v = ((unsigned int)u) << 16;
    return __builtin_bit_cast(float, v);
}

// ---------------------------------------------------------------------------
// c-permutation shared by pack_weights and pool staging:
// cb (0..127 = c-block of 8), elem j (0..7):
//   c = (cb>>5)*256 + ((cb>>3)&3)*64 + (cb&7) + 8*j
// GEMM contraction order over c is free as long as Wpk uses the SAME perm.
// ---------------------------------------------------------------------------

// ---------------------------------------------------------------------------
// K1 v5: pack Wpool/Wconv into MFMA A-fragment order.  Grid (9, 8).
// ---------------------------------------------------------------------------
__global__ __launch_bounds__(256)
void pack_weights(const float* __restrict__ Wpool, const float* __restrict__ Wconv,
                  unsigned short* __restrict__ Wpk, unsigned short* __restrict__ Wck)
{
    const int b = blockIdx.x;
    const int t = threadIdx.x;
    if (b < 8) {
        const int i = blockIdx.y;              // 0..7
        const int id = t + 256 * i;            // 0..2047
        const int ktl = id >> 9;               // 0..3
        const int mt  = (id >> 6) & 7;
        const int l   = id & 63;
        const int lm = l & 15, quad = l >> 4;
        const int kt = b * 4 + ktl;
        const int d = mt * 16 + lm;
        const int cb = kt * 4 + quad;          // 0..127
        const int base_c = (cb >> 5) * 256 + ((cb >> 3) & 3) * 64 + (cb & 7);
        float v[8];
#pragma unroll
        for (int j = 0; j < 8; j++) v[j] = Wpool[(size_t)d * CC + base_c + 8 * j];
        unsigned int* dst = (unsigned int*)&Wpk[(size_t)((kt * 8 + mt) * 64 + l) * 8];
        dst[0] = pk_bf16(v[0], v[1]); dst[1] = pk_bf16(v[2], v[3]);
        dst[2] = pk_bf16(v[4], v[5]); dst[3] = pk_bf16(v[6], v[7]);
    } else if (blockIdx.y < 4) {
        const int i = blockIdx.y;              // 0..3
        const int id = t + 256 * i;            // 0..1023
        const int tile = id >> 6;
        const int l = id & 63;
        const int lm = l & 15, quad = l >> 4;
        const int k = (tile >> 2) * 16 + lm;
        const int d = (tile & 3) * 32 + quad * 8;
        const float4 v0 = *(const float4*)&Wconv[(size_t)k * DD + d];
        const float4 v1 = *(const float4*)&Wconv[(size_t)k * DD + d + 4];
        unsigned int* dst = (unsigned int*)&Wck[(size_t)(tile * 64 + l) * 8];
        dst[0] = pk_bf16(v0.x, v0.y); dst[1] = pk_bf16(v0.z, v0.w);
        dst[2] = pk_bf16(v1.x, v1.y); dst[3] = pk_bf16(v1.z, v1.w);
    }
}

// ---------------------------------------------------------------------------
// K2 v5 (unchanged): pool GEMM + bias + L2-norm + assign GEMM + softmax.
// LDS 33.25 KB via aliasing; 4 blocks/CU; sched_barrier fences pin
// issue-early/consume-late staging.
// ---------------------------------------------------------------------------
__global__ __launch_bounds__(256, 4)
void pool_norm_assign(const float* __restrict__ x, const unsigned short* __restrict__ Wpk,
                      const float* __restrict__ bpool, const unsigned short* __restrict__ Wck,
                      const float* __restrict__ bconv,
                      unsigned short* __restrict__ xn, unsigned short* __restrict__ sa)
{
    const int n  = blockIdx.y;
    const int s0 = blockIdx.x * 32;
    const int t  = threadIdx.x;
    const int l  = t & 63;
    const int w  = t >> 6;       // wave 0..3
    const int lm = l & 15;
    const int quad = l >> 4;

    // 33.25 KB total: Bst0 (16 KB) | Bst1 (16 KB) | red/sums (1 KB)
    __shared__ alignas(16) unsigned char smem[2 * 32 * 32 * 8 * 2 + 4 * 32 * 4];
    unsigned short* Bst0 = (unsigned short*)smem;
    unsigned short* Bst1 = Bst0 + 32 * 32 * 8;
    unsigned short* xnT  = Bst0;                      // alias (see header)
    float* red  = (float*)(smem + 2 * 32 * 32 * 8 * 2);  // [4][32]
    float* sums = red;                                   // alias (see header)

    unsigned short* xnp = xn + (size_t)n * DD * SP;
    unsigned short* sap = sa + (size_t)n * KK * SP;

    if (s0 >= SS) {
        // pure-pad tile (s0 = 800): zero xn and sa for s 800..831, exit.
        const u32x4 z = (u32x4){0u, 0u, 0u, 0u};
#pragma unroll
        for (int pp = 0; pp < 2; pp++) {
            const int idx = t + 256 * pp;
            *(u32x4*)&xnp[(size_t)(idx >> 2) * SP + s0 + (idx & 3) * 8] = z;
        }
        *(u32x4*)&sap[(size_t)(t >> 2) * SP + s0 + (t & 3) * 8] = z;
        return;
    }

    const int r0 = (l >> 3) & 7;   // row-in-group 0..7
    const int se = l & 7;          // 16B s-chunk 0..7
    // chunk-aligned clamp for the mixed tile 24 (s 784..799 OOB -> reload
    // an in-bounds chunk; values garbage-but-finite, neutralized by sa=0)
    int sc = s0 + se * 4;
    if (sc + 4 > SS) sc = s0 + (se & 3) * 4;
    const float* xw = x + (size_t)n * CC * SS + sc;
    const int crow0 = w * 64 + r0;                 // + q*256 + j*8 = global c row

    // ---- prologue: issue quarter-0 x loads + Wpk depth-4 prefetch, THEN pack
    f32x4 g[8];
#pragma unroll
    for (int j = 0; j < 8; j++)
        g[j] = *(const f32x4*)&xw[(size_t)(crow0 + j * 8) * SS];

    bf16x8 abuf[4][2];  // prefetch depth 4: slot kt&3
#pragma unroll
    for (int p = 0; p < 4; p++)
#pragma unroll
        for (int i = 0; i < 2; i++)
            abuf[p][i] = *(const bf16x8*)&Wpk[(size_t)((p * 8 + w * 2 + i) * 64 + l) * 8];

    __builtin_amdgcn_sched_barrier(0);

#pragma unroll
    for (int ss = 0; ss < 4; ss++) {
        const int s = se * 4 + ss;
        const int sig = s ^ ((s >> 3) & 3);
        unsigned int* dst = (unsigned int*)&Bst0[(size_t)((w * 8 + r0) * 32 + sig) * 8];
        dst[0] = pk_bf16(g[0][ss], g[1][ss]); dst[1] = pk_bf16(g[2][ss], g[3][ss]);
        dst[2] = pk_bf16(g[4][ss], g[5][ss]); dst[3] = pk_bf16(g[6][ss], g[7][ss]);
    }
    __syncthreads();

    f32x4 acc[2][2];   // [i=d-tile][h=s-sub]
#pragma unroll
    for (int i = 0; i < 2; i++)
#pragma unroll
        for (int h = 0; h < 2; h++) acc[i][h] = (f32x4){0.f, 0.f, 0.f, 0.f};

    for (int q = 0; q < 4; ++q) {
        // issue next-quarter x loads (consumed only after this K-loop)
        if (q < 3) {
#pragma unroll
            for (int j = 0; j < 8; j++)
                g[j] = *(const f32x4*)&xw[(size_t)((q + 1) * 256 + crow0 + j * 8) * SS];
        }
        __builtin_amdgcn_sched_barrier(0);   // loads stay ABOVE the K-loop
        const unsigned short* Bq = (q & 1) ? Bst1 : Bst0;
#pragma unroll
        for (int ktq = 0; ktq < 8; ++ktq) {
            const int kt = q * 8 + ktq;
            const bf16x8 a0 = abuf[ktq & 3][0], a1 = abuf[ktq & 3][1];
            if (kt < 28) {
#pragma unroll
                for (int i = 0; i < 2; i++)
                    abuf[ktq & 3][i] = *(const bf16x8*)&Wpk[(size_t)(((kt + 4) * 8 + w * 2 + i) * 64 + l) * 8];
            }
#pragma unroll
            for (int h = 0; h < 2; h++) {
                const int s = h * 16 + lm;
                const int sig = s ^ ((s >> 3) & 3);
                const bf16x8 bf = *(const bf16x8*)&Bq[(size_t)((ktq * 4 + quad) * 32 + sig) * 8];
                acc[0][h] = __builtin_amdgcn_mfma_f32_16x16x32_bf16(a0, bf, acc[0][h], 0, 0, 0);
                acc[1][h] = __builtin_amdgcn_mfma_f32_16x16x32_bf16(a1, bf, acc[1][h], 0, 0, 0);
            }
        }
        __builtin_amdgcn_sched_barrier(0);   // packs stay BELOW the K-loop
        if (q < 3) {
            unsigned short* Bn = ((q + 1) & 1) ? Bst1 : Bst0;
#pragma unroll
            for (int ss = 0; ss < 4; ss++) {
                const int s = se * 4 + ss;
                const int sig = s ^ ((s >> 3) & 3);
                unsigned int* dst = (unsigned int*)&Bn[(size_t)((w * 8 + r0) * 32 + sig) * 8];
                dst[0] = pk_bf16(g[0][ss], g[1][ss]); dst[1] = pk_bf16(g[2][ss], g[3][ss]);
                dst[2] = pk_bf16(g[4][ss], g[5][ss]); dst[3] = pk_bf16(g[6][ss], g[7][ss]);
            }
        }
        __syncthreads();
    }

    // ---- PHASE 3a: bias + L2-norm over d.  C: d=(2w+i)*16+quad*4+r, s=h*16+lm
    float vals[2][2][4];
    float ssq[2] = {0.f, 0.f};
#pragma unroll
    for (int i = 0; i < 2; i++)
#pragma unroll
        for (int h = 0; h < 2; h++)
#pragma unroll
            for (int r = 0; r < 4; r++) {
                const int d = (w * 2 + i) * 16 + quad * 4 + r;
                const float v = acc[i][h][r] + bpool[d];
                vals[i][h][r] = v; ssq[h] += v * v;
            }
#pragma unroll
    for (int h = 0; h < 2; h++) {
        ssq[h] += __shfl_xor(ssq[h], 16, 64);
        ssq[h] += __shfl_xor(ssq[h], 32, 64);
    }
    if (quad == 0) { red[w * 32 + lm] = ssq[0]; red[w * 32 + 16 + lm] = ssq[1]; }
    __syncthreads();
    float scale[2];
#pragma unroll
    for (int h = 0; h < 2; h++) {
        const int sl = h * 16 + lm;
        scale[h] = 1.f / fmaxf(sqrtf(red[0 * 32 + sl] + red[1 * 32 + sl] + red[2 * 32 + sl] + red[3 * 32 + sl]), 1e-12f);
    }
    // red reads complete here for all threads before the next barrier;
    // xnT (aliasing Bst0, last read 2 barriers ago) is written now.
#pragma unroll
    for (int i = 0; i < 2; i++)
#pragma unroll
        for (int h = 0; h < 2; h++)
#pragma unroll
            for (int r = 0; r < 4; r++) {
                const int d = (w * 2 + i) * 16 + quad * 4 + r;
                const int sg = s0 + h * 16 + lm;
                const float v = vals[i][h][r] * scale[h];
                xnp[(size_t)d * SP + sg] = f2bf(v);
                xnT[(size_t)(((d >> 3) * 32) + h * 16 + lm) * 8 + (d & 7)] = f2bf(v);
            }
    __syncthreads();

    // ---- PHASE 3b: assign GEMM (64k x 32s), wave w -> k-tile w
    f32x4 acc2[2];
    acc2[0] = (f32x4){0.f, 0.f, 0.f, 0.f};
    acc2[1] = (f32x4){0.f, 0.f, 0.f, 0.f};
#pragma unroll
    for (int dsv = 0; dsv < 4; dsv++) {
        const bf16x8 afrag = *(const bf16x8*)&Wck[(size_t)((w * 4 + dsv) * 64 + l) * 8];
#pragma unroll
        for (int h = 0; h < 2; h++) {
            const bf16x8 bfrag = *(const bf16x8*)&xnT[(size_t)((dsv * 4 + quad) * 32 + h * 16 + lm) * 8];
            acc2[h] = __builtin_amdgcn_mfma_f32_16x16x32_bf16(afrag, bfrag, acc2[h], 0, 0, 0);
        }
    }
    // softmax over k (|logits| small since x-hat unit-norm: no max-sub needed)
    float e[2][4]; float ps[2] = {0.f, 0.f};
#pragma unroll
    for (int h = 0; h < 2; h++)
#pragma unroll
        for (int r = 0; r < 4; r++) {
            const int k = w * 16 + quad * 4 + r;
            e[h][r] = expf(acc2[h][r] + bconv[k]);
            ps[h] += e[h][r];
        }
#pragma unroll
    for (int h = 0; h < 2; h++) {
        ps[h] += __shfl_xor(ps[h], 16, 64);
        ps[h] += __shfl_xor(ps[h], 32, 64);
    }
    if (quad == 0) { sums[w * 32 + lm] = ps[0]; sums[w * 32 + 16 + lm] = ps[1]; }
    __syncthreads();
#pragma unroll
    for (int h = 0; h < 2; h++) {
        const int sl = h * 16 + lm;
        const int sg = s0 + sl;
        const float inv = 1.f / (sums[0 * 32 + sl] + sums[1 * 32 + sl] + sums[2 * 32 + sl] + sums[3 * 32 + sl]);
        const bool val2 = sg < SS;
#pragma unroll
        for (int r = 0; r < 4; r++) {
            const int k = w * 16 + quad * 4 + r;
            sap[(size_t)k * SP + sg] = val2 ? f2bf(e[h][r] * inv) : (unsigned short)0;
        }
    }
}

// ---------------------------------------------------------------------------
// K3 v6b (vlad_full): FUSED vlad GEMM + sasum + centroid subtract + k-norm.
// grid (DD/16=8 d-groups, N) = 256 blocks; wave w owns k-tile w (16 k),
// block owns 16 d; 26 MFMA K-steps of 32 s as a NAMED 2-stage ping-pong
// (afA/bfA, afB/bfB — proj_mfma's proven LA/LB pattern; no indexed buffer
// arrays, no scratch risk).  sasum computed inline from the same
// A-fragments.  Eliminates the vladp write+read round-trip, sasump, and one
// launch.  sa pad region is 0 (K2 guarantees), so pad s contributes 0.
// ---------------------------------------------------------------------------
__global__ __launch_bounds__(256)
void vlad_full(const unsigned short* __restrict__ xn, const unsigned short* __restrict__ sa,
               const float* __restrict__ centroids, float* __restrict__ vladn)
{
    const int dg = blockIdx.x;     // 0..7, d = dg*16 + lm
    const int n  = blockIdx.y;
    const int t  = threadIdx.x;
    const int l  = t & 63;
    const int w  = t >> 6;         // k-tile 0..3
    const int lm = l & 15, quad = l >> 4;

    __shared__ float sas[KK];
    __shared__ float red[4][16];

    const unsigned short* sap = sa + (size_t)n * KK * SP + (size_t)(w * 16 + lm) * SP + quad * 8;
    const unsigned short* xnp = xn + (size_t)n * DD * SP + (size_t)(dg * 16 + lm) * SP + quad * 8;

    f32x4 acc = (f32x4){0.f, 0.f, 0.f, 0.f};
    float ssum = 0.f;

    bf16x8 afA, bfA, afB, bfB;     // named 2-stage ping-pong
    afA = *(const bf16x8*)&sap[0];
    bfA = *(const bf16x8*)&xnp[0];
    afB = *(const bf16x8*)&sap[32];
    bfB = *(const bf16x8*)&xnp[32];
    __builtin_amdgcn_sched_barrier(0);

#pragma unroll
    for (int st = 0; st < 26; st += 2) {
        const bf16x8 a0 = afA, b0 = bfA;
        if (st + 2 < 26) {
            afA = *(const bf16x8*)&sap[(st + 2) * 32];
            bfA = *(const bf16x8*)&xnp[(st + 2) * 32];
        }
        acc = __builtin_amdgcn_mfma_f32_16x16x32_bf16(a0, b0, acc, 0, 0, 0);
#pragma unroll
        for (int j = 0; j < 8; j++) ssum += bf2f((unsigned short)a0[j]);

        const bf16x8 a1 = afB, b1 = bfB;
        if (st + 3 < 26) {
            afB = *(const bf16x8*)&sap[(st + 3) * 32];
            bfB = *(const bf16x8*)&xnp[(st + 3) * 32];
        }
        acc = __builtin_amdgcn_mfma_f32_16x16x32_bf16(a1, b1, acc, 0, 0, 0);
#pragma unroll
        for (int j = 0; j < 8; j++) ssum += bf2f((unsigned short)a1[j]);
    }

    // sasum[k]: lanes sharing lm hold row k=w*16+lm; quads cover disjoint s.
    ssum += __shfl_xor(ssum, 16, 64);
    ssum += __shfl_xor(ssum, 32, 64);
    if (quad == 0) sas[w * 16 + lm] = ssum;
    __syncthreads();

    // C layout: col lm -> d, row quad*4+r -> k within tile.
    float v[4]; float ssq = 0.f;
    const int d = dg * 16 + lm;
#pragma unroll
    for (int r = 0; r < 4; r++) {
        const int k = w * 16 + quad * 4 + r;
        v[r] = acc[r] - centroids[(size_t)k * DD + d] * sas[k];
        ssq += v[r] * v[r];
    }
    ssq += __shfl_xor(ssq, 16, 64);
    ssq += __shfl_xor(ssq, 32, 64);
    if (quad == 0) red[w][lm] = ssq;
    __syncthreads();
    const float tot = red[0][lm] + red[1][lm] + red[2][lm] + red[3][lm];
    const float scale = 1.f / fmaxf(sqrtf(tot), 1e-12f);

    float* vo = vladn + (size_t)n * KD;
#pragma unroll
    for (int r = 0; r < 4; r++) {
        const int k = w * 16 + quad * 4 + r;
        vo[(size_t)k * DD + d] = v[r] * scale;
    }
}

// ---------------------------------------------------------------------------
// K5: projection via MFMA.  PSPLIT 16: halves outp traffic; 16 K-steps with
// the 2-stage LA/LB pipeline.  grid (16, 16) = 256 blocks.
// ---------------------------------------------------------------------------
#define PROJ_ISSUE(L, KT) do {                                              \
    const int c_ = (KT) * 32;                                               \
    L[0] = *(const f32x4*)&wrow[c_];  L[1] = *(const f32x4*)&wrow[c_ + 4];  \
    L[2] = *(const f32x4*)&arow0[c_]; L[3] = *(const f32x4*)&arow0[c_ + 4]; \
    L[4] = *(const f32x4*)&arow1[c_]; L[5] = *(const f32x4*)&arow1[c_ + 4]; \
} while (0)

#define PROJ_STEP(L) do {                                                    \
    union { unsigned int u[4]; bf16x8 v; } ub, ua0, ua1;                     \
    ub.u[0]  = pk_bf16(L[0][0], L[0][1]); ub.u[1]  = pk_bf16(L[0][2], L[0][3]); \
    ub.u[2]  = pk_bf16(L[1][0], L[1][1]); ub.u[3]  = pk_bf16(L[1][2], L[1][3]); \
    ua0.u[0] = pk_bf16(L[2][0], L[2][1]); ua0.u[1] = pk_bf16(L[2][2], L[2][3]); \
    ua0.u[2] = pk_bf16(L[3][0], L[3][1]); ua0.u[3] = pk_bf16(L[3][2], L[3][3]); \
    ua1.u[0] = pk_bf16(L[4][0], L[4][1]); ua1.u[1] = pk_bf16(L[4][2], L[4][3]); \
    ua1.u[2] = pk_bf16(L[5][0], L[5][1]); ua1.u[3] = pk_bf16(L[5][2], L[5][3]); \
    acc[0] = __builtin_amdgcn_mfma_f32_16x16x32_bf16(ua0.v, ub.v, acc[0], 0, 0, 0); \
    acc[1] = __builtin_amdgcn_mfma_f32_16x16x32_bf16(ua1.v, ub.v, acc[1], 0, 0, 0); \
} while (0)

__global__ __launch_bounds__(256)
void proj_mfma(const float* __restrict__ vladn, const float* __restrict__ Wproj,
               float* __restrict__ outp)
{
    const int o0 = blockIdx.x * 64;
    const int c0 = blockIdx.y * (KD / PSPLIT);   // 512-wide c slice
    const int t  = threadIdx.x;
    const int l  = t & 63;
    const int w  = t >> 6;
    const int lm = l & 15, quad = l >> 4;
    const int o  = o0 + w * 16 + lm;

    const float* wrow  = &Wproj[(size_t)o * KD + c0 + quad * 8];
    const float* arow0 = &vladn[(size_t)lm * KD + c0 + quad * 8];
    const float* arow1 = &vladn[(size_t)(16 + lm) * KD + c0 + quad * 8];

    f32x4 acc[2];
    acc[0] = (f32x4){0.f, 0.f, 0.f, 0.f};
    acc[1] = (f32x4){0.f, 0.f, 0.f, 0.f};

    f32x4 LA[6], LB[6];
    PROJ_ISSUE(LA, 0);
#pragma unroll
    for (int kt = 0; kt < 16; kt += 2) {
        PROJ_ISSUE(LB, kt + 1);
        __builtin_amdgcn_sched_barrier(0);
        PROJ_STEP(LA);
        if (kt + 2 < 16) PROJ_ISSUE(LA, kt + 2);
        __builtin_amdgcn_sched_barrier(0);
        PROJ_STEP(LB);
    }

    // C layout: col lm -> o (matches B), row quad*4+r -> n = a*16+quad*4+r
#pragma unroll
    for (int a = 0; a < 2; a++)
#pragma unroll
        for (int r = 0; r < 4; r++) {
            const int nn = a * 16 + quad * 4 + r;
            outp[((size_t)blockIdx.y * NB + nn) * OUTD + o] = acc[a][r];
        }
}

// ---------------------------------------------------------------------------
// K6: sum projection partials + bproj, final L2 norm over OUT, write d_out.
// PSPLIT=16: single 16-wide batched load set.
// ---------------------------------------------------------------------------
__global__ __launch_bounds__(256)
void final_norm_kernel(const float* __restrict__ outp, const float* __restrict__ bproj,
                       float* __restrict__ out)
{
    const int n = blockIdx.x;
    const int t = threadIdx.x;
    const int o4 = t * 4;

    float4 a = *(const float4*)&bproj[o4];
    f32x4 pr[PSPLIT];
#pragma unroll
    for (int i = 0; i < PSPLIT; i++)
        pr[i] = *(const f32x4*)&outp[((size_t)i * NB + n) * OUTD + o4];
    __builtin_amdgcn_sched_barrier(0);
#pragma unroll
    for (int i = 0; i < PSPLIT; i++) {
        a.x += pr[i][0]; a.y += pr[i][1]; a.z += pr[i][2]; a.w += pr[i][3];
    }
    float ssp = a.x * a.x + a.y * a.y + a.z * a.z + a.w * a.w;
#pragma unroll
    for (int off = 32; off > 0; off >>= 1) ssp += __shfl_down(ssp, off, 64);
    __shared__ float rs[4];
    if ((t & 63) == 0) rs[t >> 6] = ssp;
    __syncthreads();
    const float total = rs[0] + rs[1] + rs[2] + rs[3];
    const float scale = 1.f / fmaxf(sqrtf(total), 1e-12f);
    float4 o;
    o.x = a.x * scale; o.y = a.y * scale; o.z = a.z * scale; o.w = a.w * scale;
    *(float4*)&out[(size_t)n * OUTD + o4] = o;
}

// ---------------------------------------------------------------------------
extern "C" void kernel_launch(void* const* d_in, const int* in_sizes, int n_in,
                              void* d_out, int out_size, void* d_ws, size_t ws_size,
                              hipStream_t stream)
{
    const float* x         = (const float*)d_in[0];
    const float* Wpool     = (const float*)d_in[1];
    const float* bpool     = (const float*)d_in[2];
    const float* Wconv     = (const float*)d_in[3];
    const float* bconv     = (const float*)d_in[4];
    const float* centroids = (const float*)d_in[5];
    const float* Wproj     = (const float*)d_in[6];
    const float* bproj     = (const float*)d_in[7];
    float* out = (float*)d_out;
    char*  wsb = (char*)d_ws;

    unsigned short* xn     = (unsigned short*)(wsb + OFF_XN);
    unsigned short* sa     = (unsigned short*)(wsb + OFF_SA);
    unsigned short* Wpk    = (unsigned short*)(wsb + OFF_WPK);
    unsigned short* Wck    = (unsigned short*)(wsb + OFF_WCK);
    float*          vladn  = (float*)(wsb + OFF_VLADN);
    float*          outp   = (float*)(wsb + OFF_OUTP);

    pack_weights<<<dim3(9, 8), 256, 0, stream>>>(Wpool, Wconv, Wpk, Wck);
    pool_norm_assign<<<dim3(26, NB), 256, 0, stream>>>(x, Wpk, bpool, Wck, bconv, xn, sa);
    vlad_full<<<dim3(DD / 16, NB), 256, 0, stream>>>(xn, sa, centroids, vladn);
    proj_mfma<<<dim3(OUTD / 64, PSPLIT), 256, 0, stream>>>(vladn, Wproj, outp);
    final_norm_kernel<<<dim3(NB), 256, 0, stream>>>(outp, bproj, out);
}